// Round 7
// baseline (14032.236 us; speedup 1.0000x reference)
//
#include <hip/hip_runtime.h>
#include <cstdint>
#include <cstddef>

#define DEVINL __device__ __forceinline__

typedef float f32x4 __attribute__((ext_vector_type(4)));

DEVINL f32x4 ntload4(const float* p) {
    return __builtin_nontemporal_load((const f32x4*)p);
}
DEVINL float ntload1(const float* p) {
    return __builtin_nontemporal_load(p);
}
DEVINL f32x4 ld4(const float* p) {
    return *reinterpret_cast<const f32x4*>(p);
}

// ---------- math helpers ----------
DEVINL float frcp(float x) { return __builtin_amdgcn_rcpf(x); }
DEVINL float ftanh_fast(float x) {
    float e = __expf(2.0f * x);
    return 1.0f - 2.0f * frcp(e + 1.0f);
}
DEVINL float sig_precise(float x) { return 1.0f / (1.0f + expf(-x)); }
DEVINL float tanh_precise(float x) { return tanhf(x); }

// ---------- sizes ----------
#define BB 128
#define SS 128
#define IND 16
#define DD 256
#define HH 256
#define H4 1024
#define H2 512

// =====================================================================
// K1: emb = LayerNorm(tanh(x @ proj_W.T + proj_b))   (one block per row)
// =====================================================================
__global__ __launch_bounds__(256) void k_proj_ln(
    const float* __restrict__ x, const float* __restrict__ projW,
    const float* __restrict__ projB, const float* __restrict__ ln_g,
    const float* __restrict__ ln_b, float* __restrict__ emb)
{
    __shared__ float Wl[256 * 17];
    __shared__ float xl[16];
    __shared__ float red[256];
    const int row = blockIdx.x;
    const int tid = threadIdx.x;
    for (int idx = tid; idx < 256 * 16; idx += 256) {
        int d = idx >> 4, i = idx & 15;
        Wl[d * 17 + i] = projW[idx];
    }
    if (tid < 16) xl[tid] = x[row * 16 + tid];
    __syncthreads();
    float acc = projB[tid];
#pragma unroll
    for (int i = 0; i < 16; ++i) acc = fmaf(Wl[tid * 17 + i], xl[i], acc);
    float v = tanh_precise(acc);
    red[tid] = v;
    __syncthreads();
    for (int s2 = 128; s2 > 0; s2 >>= 1) { if (tid < s2) red[tid] += red[tid + s2]; __syncthreads(); }
    float mean = red[0] * (1.0f / 256.0f);
    __syncthreads();
    float dlt = v - mean;
    red[tid] = dlt * dlt;
    __syncthreads();
    for (int s2 = 128; s2 > 0; s2 >>= 1) { if (tid < s2) red[tid] += red[tid + s2]; __syncthreads(); }
    float var = red[0] * (1.0f / 256.0f);
    float rs = 1.0f / sqrtf(var + 1e-5f);
    emb[(size_t)row * 256 + tid] = dlt * rs * ln_g[tid] + ln_b[tid];
}

// =====================================================================
// K2: generic fp32 GEMM-NT  C(MxN) = A(MxK,lda) * B(NxK)^T (+bias1+bias2)
// =====================================================================
__global__ __launch_bounds__(256) void k_gemm_nt(
    const float* __restrict__ A, int lda,
    const float* __restrict__ Bm,
    float* __restrict__ C,
    int M, int N, int K,
    const float* __restrict__ bias1, const float* __restrict__ bias2,
    int flags)
{
    __shared__ __align__(16) float As[16][132];
    __shared__ __align__(16) float Bs[16][132];
    const int tid = threadIdx.x;
    const int m0 = blockIdx.x * 128;
    const int n0 = blockIdx.y * 128;
    const int r = tid >> 1, half = tid & 1;
    const int tm = tid & 15, tn = tid >> 4;
    float acc[8][8];
#pragma unroll
    for (int i = 0; i < 8; ++i)
#pragma unroll
        for (int j = 0; j < 8; ++j) acc[i][j] = 0.0f;

    for (int k0 = 0; k0 < K; k0 += 16) {
        const float4* pa = reinterpret_cast<const float4*>(&A[(size_t)(m0 + r) * lda + k0 + half * 8]);
        float4 a0 = pa[0], a1 = pa[1];
        const float4* pb = reinterpret_cast<const float4*>(&Bm[(size_t)(n0 + r) * K + k0 + half * 8]);
        float4 b0 = pb[0], b1 = pb[1];
        __syncthreads();
        const int kb = half * 8;
        As[kb + 0][r] = a0.x; As[kb + 1][r] = a0.y; As[kb + 2][r] = a0.z; As[kb + 3][r] = a0.w;
        As[kb + 4][r] = a1.x; As[kb + 5][r] = a1.y; As[kb + 6][r] = a1.z; As[kb + 7][r] = a1.w;
        Bs[kb + 0][r] = b0.x; Bs[kb + 1][r] = b0.y; Bs[kb + 2][r] = b0.z; Bs[kb + 3][r] = b0.w;
        Bs[kb + 4][r] = b1.x; Bs[kb + 5][r] = b1.y; Bs[kb + 6][r] = b1.z; Bs[kb + 7][r] = b1.w;
        __syncthreads();
#pragma unroll
        for (int kk = 0; kk < 16; ++kk) {
            const float4 xa0 = *reinterpret_cast<const float4*>(&As[kk][tm * 8]);
            const float4 xa1 = *reinterpret_cast<const float4*>(&As[kk][tm * 8 + 4]);
            const float4 xb0 = *reinterpret_cast<const float4*>(&Bs[kk][tn * 8]);
            const float4 xb1 = *reinterpret_cast<const float4*>(&Bs[kk][tn * 8 + 4]);
            const float av[8] = {xa0.x, xa0.y, xa0.z, xa0.w, xa1.x, xa1.y, xa1.z, xa1.w};
            const float bv[8] = {xb0.x, xb0.y, xb0.z, xb0.w, xb1.x, xb1.y, xb1.z, xb1.w};
#pragma unroll
            for (int i = 0; i < 8; ++i)
#pragma unroll
                for (int j = 0; j < 8; ++j) acc[i][j] = fmaf(av[i], bv[j], acc[i][j]);
        }
    }
    const int nb = n0 + tn * 8;
    float bias[8];
#pragma unroll
    for (int j = 0; j < 8; ++j) {
        float bbv = 0.0f;
        if (bias1) bbv += bias1[nb + j];
        if (bias2) bbv += bias2[nb + j];
        bias[j] = bbv;
    }
#pragma unroll
    for (int i = 0; i < 8; ++i) {
        const size_t m = (size_t)(m0 + tm * 8 + i);
        float o[8];
#pragma unroll
        for (int j = 0; j < 8; ++j) {
            float vv = acc[i][j] + bias[j];
            if (flags & 1) vv = tanh_precise(vv);
            o[j] = vv;
        }
        float4* pc = reinterpret_cast<float4*>(&C[m * N + nb]);
        pc[0] = make_float4(o[0], o[1], o[2], o[3]);
        pc[1] = make_float4(o[4], o[5], o[6], o[7]);
    }
}

// =====================================================================
// K3: bidirectional LSTM; grid 128 = 2 dirs * 64 groups; 512 threads;
// 2 batches/WG; per-WG q-stagger on the W pass (anti-convoy).
// =====================================================================
__global__ __launch_bounds__(512, 2) void k_lstm(
    const float* __restrict__ Whh_f, const float* __restrict__ Whh_b,
    const float* __restrict__ xf, const float* __restrict__ xb,
    float* __restrict__ enc, float* __restrict__ hT, float* __restrict__ cT)
{
    const int wg = blockIdx.x;       // 0..127
    const int dir = wg >> 6;
    const int grp = wg & 63;
    const int bb0 = grp * 2;
    const int off = wg & 15;         // q-stagger
    const float* W = dir ? Whh_b : Whh_f;
    const float* xin = dir ? xb : xf;
    const int tid = threadIdx.x;
    const int oct = tid & 7, jg = tid >> 3;   // jg 0..63
    const int gc = tid & 255, gb = tid >> 8;

    __shared__ __align__(16) float h_lds[2][256];
    __shared__ float pre_lds[2][1024];

    for (int i = tid; i < 2 * 256; i += 512) (&h_lds[0][0])[i] = 0.0f;
    float c_reg = 0.0f;
    __syncthreads();

    for (int t = 0; t < SS; ++t) {
        const int st = dir ? (SS - 1 - t) : t;
        float hreg[2][32];
#pragma unroll
        for (int bsel = 0; bsel < 2; ++bsel) {
#pragma unroll
            for (int i = 0; i < 8; ++i) {
                float4 v = *reinterpret_cast<const float4*>(&h_lds[bsel][i * 32 + oct * 4]);
                hreg[bsel][i * 4 + 0] = v.x; hreg[bsel][i * 4 + 1] = v.y;
                hreg[bsel][i * 4 + 2] = v.z; hreg[bsel][i * 4 + 3] = v.w;
            }
        }
        // W pass: 16 q-rounds of 64 rows, staggered start, 1-ahead prefetch
        float4 wb[8];
        {
            const float* bp = &W[(size_t)(off * 64 + jg) * 256 + oct * 4];
#pragma unroll
            for (int i = 0; i < 8; ++i) wb[i] = *reinterpret_cast<const float4*>(bp + i * 32);
        }
        for (int q = 0; q < 16; ++q) {
            const int qs = (q + off) & 15;
            float4 wn[8];
            if (q < 15) {
                const int qs2 = (q + 1 + off) & 15;
                const float* bp = &W[(size_t)(qs2 * 64 + jg) * 256 + oct * 4];
#pragma unroll
                for (int i = 0; i < 8; ++i) wn[i] = *reinterpret_cast<const float4*>(bp + i * 32);
            }
            float a0 = 0.0f, a1 = 0.0f;
#pragma unroll
            for (int i = 0; i < 8; ++i) {
                a0 = fmaf(wb[i].x, hreg[0][i * 4 + 0], a0);
                a0 = fmaf(wb[i].y, hreg[0][i * 4 + 1], a0);
                a0 = fmaf(wb[i].z, hreg[0][i * 4 + 2], a0);
                a0 = fmaf(wb[i].w, hreg[0][i * 4 + 3], a0);
                a1 = fmaf(wb[i].x, hreg[1][i * 4 + 0], a1);
                a1 = fmaf(wb[i].y, hreg[1][i * 4 + 1], a1);
                a1 = fmaf(wb[i].z, hreg[1][i * 4 + 2], a1);
                a1 = fmaf(wb[i].w, hreg[1][i * 4 + 3], a1);
            }
            a0 += __shfl_xor(a0, 1); a0 += __shfl_xor(a0, 2); a0 += __shfl_xor(a0, 4);
            a1 += __shfl_xor(a1, 1); a1 += __shfl_xor(a1, 2); a1 += __shfl_xor(a1, 4);
            if (oct == 0) {
                const int row = qs * 64 + jg;
                pre_lds[0][row] = a0; pre_lds[1][row] = a1;
            }
#pragma unroll
            for (int i = 0; i < 8; ++i) wb[i] = wn[i];
        }
        __syncthreads();
        {
            const float* xrow = &xin[((size_t)(bb0 + gb) * SS + st) * 1024];
            float pi = pre_lds[gb][gc]       + ntload1(&xrow[gc]);
            float pf = pre_lds[gb][256 + gc] + ntload1(&xrow[256 + gc]);
            float pg = pre_lds[gb][512 + gc] + ntload1(&xrow[512 + gc]);
            float po = pre_lds[gb][768 + gc] + ntload1(&xrow[768 + gc]);
            float ig = sig_precise(pi), fg = sig_precise(pf);
            float gg = tanh_precise(pg), og = sig_precise(po);
            float cn = fmaf(fg, c_reg, ig * gg);
            float hn = og * tanh_precise(cn);
            c_reg = cn;
            h_lds[gb][gc] = hn;
            enc[((size_t)(bb0 + gb) * SS + st) * 512 + dir * 256 + gc] = hn;
            if (t == SS - 1) {
                hT[(size_t)(bb0 + gb) * 512 + dir * 256 + gc] = hn;
                cT[(size_t)(bb0 + gb) * 512 + dir * 256 + gc] = cn;
            }
        }
        __syncthreads();
    }
}

// =====================================================================
// K5: pre0[b][j] = mean_s encW[b][s][j]
// =====================================================================
__global__ __launch_bounds__(256) void k_meanw(const float* __restrict__ encW, float* __restrict__ pre0)
{
    const int b = blockIdx.x;
    const int tid = threadIdx.x;
    const float4* base = reinterpret_cast<const float4*>(&encW[(size_t)b * SS * 1024]);
    float sx = 0.0f, sy = 0.0f, sz = 0.0f, sw = 0.0f;
    for (int s = 0; s < SS; ++s) {
        float4 v = base[s * 256 + tid];
        sx += v.x; sy += v.y; sz += v.z; sw += v.w;
    }
    float4* out = reinterpret_cast<float4*>(&pre0[(size_t)b * 1024]);
    out[tid] = make_float4(sx * (1.0f / 128.0f), sy * (1.0f / 128.0f), sz * (1.0f / 128.0f), sw * (1.0f / 128.0f));
}

// =====================================================================
// K6: pointer decoder, 64 WGs x 2 batches, 1024 threads (4 waves/SIMD),
// 128 steps. Weight phases: no reg-prefetch (TLP hides latency),
// per-WG q-stagger (anti-convoy). Ref phases keep deep ILP. Branchless.
// =====================================================================
__global__ __launch_bounds__(1024) void k_decoder(
    const float* __restrict__ Whh_d,
    const float* __restrict__ gW2, const float* __restrict__ pW2,
    const float* __restrict__ gv, const float* __restrict__ pv,
    const float* __restrict__ g_ref, const float* __restrict__ p_ref,
    const float* __restrict__ encP, const float* __restrict__ encW,
    const float* __restrict__ pre0, const float* __restrict__ h0,
    const float* __restrict__ c0,
    float* __restrict__ out_logits, float* __restrict__ out_ptrs)
{
    const int b0 = blockIdx.x * 2;
    const int tid = threadIdx.x;
    const int oct = tid & 7, jg = tid >> 3;   // jg 0..127
    const int wid = tid >> 6, lane = tid & 63;
    const int woff = blockIdx.x & 7;          // q-stagger

    __shared__ __align__(16) float h_lds[2][256];
    __shared__ float c_lds[2][256];
    __shared__ float pre_lds[2][1024];
    __shared__ float row_lds[2][1024];
    __shared__ __align__(16) float hgp[2][512];   // [.,0..255]=hg, [.,256..511]=hp1
    __shared__ __align__(16) float hp_lds[2][256];
    __shared__ __align__(16) float gv_lds[256];
    __shared__ __align__(16) float pv_lds[256];
    __shared__ float sc_arr[2][128];
    __shared__ float e_arr[2][128];
    __shared__ __align__(16) float hp_half[8][2][256];
    __shared__ int mask_lds[2][128];
    __shared__ float Z_arr[2];
    __shared__ int sel_arr[2];

    if (tid < 256) {
        gv_lds[tid] = gv[tid];
        pv_lds[tid] = pv[tid];
#pragma unroll
        for (int bt = 0; bt < 2; ++bt) {
            h_lds[bt][tid] = h0[(size_t)(b0 + bt) * 256 + tid];
            c_lds[bt][tid] = c0[(size_t)(b0 + bt) * 256 + tid];
        }
    }
    if (tid < 128) { mask_lds[0][tid] = 0; mask_lds[1][tid] = 0; }
    if (tid < 2) sel_arr[tid] = -1;
    __syncthreads();

    for (int t = 0; t < SS; ++t) {
        // ---- stage xt rows (encW[sel] or pre0); h_{t-1} -> regs ----
#pragma unroll
        for (int rep = 0; rep < 2; ++rep) {
            const int idx = tid + rep * 1024;
            const int bt = idx >> 10, j = idx & 1023;
            const int sel = sel_arr[bt];
            const float* src = (sel < 0) ? &pre0[(size_t)(b0 + bt) * 1024]
                                         : &encW[((size_t)((b0 + bt) * SS + sel)) * 1024];
            row_lds[bt][j] = ntload1(src + j);
        }
        float hreg[2][32];
#pragma unroll
        for (int bt = 0; bt < 2; ++bt) {
#pragma unroll
            for (int i = 0; i < 8; ++i) {
                float4 v = *reinterpret_cast<const float4*>(&h_lds[bt][i * 32 + oct * 4]);
                hreg[bt][i * 4 + 0] = v.x; hreg[bt][i * 4 + 1] = v.y;
                hreg[bt][i * 4 + 2] = v.z; hreg[bt][i * 4 + 3] = v.w;
            }
        }
        __syncthreads();
        // ---- phase 1: pre = row + Whh_d @ h (8 q-rounds of 128 rows) ----
        for (int q = 0; q < 8; ++q) {
            const int qs = (q + woff) & 7;
            const int row = qs * 128 + jg;
            const float* bp = &Whh_d[(size_t)row * 256 + oct * 4];
            float4 wb[8];
#pragma unroll
            for (int i = 0; i < 8; ++i) wb[i] = *reinterpret_cast<const float4*>(bp + i * 32);
            float a0 = 0.0f, a1 = 0.0f;
#pragma unroll
            for (int i = 0; i < 8; ++i) {
                const float w4[4] = {wb[i].x, wb[i].y, wb[i].z, wb[i].w};
#pragma unroll
                for (int c = 0; c < 4; ++c) {
                    const int k = i * 4 + c;
                    a0 = fmaf(w4[c], hreg[0][k], a0);
                    a1 = fmaf(w4[c], hreg[1][k], a1);
                }
            }
            a0 += __shfl_xor(a0, 1); a0 += __shfl_xor(a0, 2); a0 += __shfl_xor(a0, 4);
            a1 += __shfl_xor(a1, 1); a1 += __shfl_xor(a1, 2); a1 += __shfl_xor(a1, 4);
            if (oct == 0) {
                pre_lds[0][row] = a0 + row_lds[0][row];
                pre_lds[1][row] = a1 + row_lds[1][row];
            }
        }
        __syncthreads();
        // ---- phase 2: gates ----
        if (tid < 512) {
            const int bt = tid >> 8, ch = tid & 255;
            float pi = pre_lds[bt][ch],        pf = pre_lds[bt][256 + ch];
            float pg = pre_lds[bt][512 + ch],  po = pre_lds[bt][768 + ch];
            float ig = sig_precise(pi), fg = sig_precise(pf);
            float gg = tanh_precise(pg), og = sig_precise(po);
            float cn = fmaf(fg, c_lds[bt][ch], ig * gg);
            float hn = og * tanh_precise(cn);
            c_lds[bt][ch] = cn;
            h_lds[bt][ch] = hn;
        }
        __syncthreads();
        // reload new h slices
        float hreg2[2][32];
#pragma unroll
        for (int bt = 0; bt < 2; ++bt) {
#pragma unroll
            for (int i = 0; i < 8; ++i) {
                float4 v = *reinterpret_cast<const float4*>(&h_lds[bt][i * 32 + oct * 4]);
                hreg2[bt][i * 4 + 0] = v.x; hreg2[bt][i * 4 + 1] = v.y;
                hreg2[bt][i * 4 + 2] = v.z; hreg2[bt][i * 4 + 3] = v.w;
            }
        }
        // ---- phase 3: hg/hp1 (4 q-rounds of 128 rows, staggered) ----
        for (int q = 0; q < 4; ++q) {
            const int qs = (q + woff) & 3;
            const int r2 = qs * 128 + jg;
            const float* src = (r2 < 256) ? &gW2[(size_t)r2 * 256] : &pW2[(size_t)(r2 - 256) * 256];
            float4 wb[8];
#pragma unroll
            for (int i = 0; i < 8; ++i) wb[i] = *reinterpret_cast<const float4*>(src + oct * 4 + i * 32);
            float a0 = 0.0f, a1 = 0.0f;
#pragma unroll
            for (int i = 0; i < 8; ++i) {
                const float w4[4] = {wb[i].x, wb[i].y, wb[i].z, wb[i].w};
#pragma unroll
                for (int c = 0; c < 4; ++c) {
                    const int k = i * 4 + c;
                    a0 = fmaf(w4[c], hreg2[0][k], a0);
                    a1 = fmaf(w4[c], hreg2[1][k], a1);
                }
            }
            a0 += __shfl_xor(a0, 1); a0 += __shfl_xor(a0, 2); a0 += __shfl_xor(a0, 4);
            a1 += __shfl_xor(a1, 1); a1 += __shfl_xor(a1, 2); a1 += __shfl_xor(a1, 4);
            if (oct == 0) {
                hgp[0][r2] = a0; hgp[1][r2] = a1;
            }
        }
        __syncthreads();
        // ---- phase 4: gs scores (2 reps: bt = rep, r = jg), deep ILP ----
        {
            const float* gr0 = &g_ref[((size_t)((b0 + 0) * SS + jg)) * 256 + oct * 4];
            const float* gr1 = &g_ref[((size_t)((b0 + 1) * SS + jg)) * 256 + oct * 4];
            f32x4 ga[8], gbx[8];
#pragma unroll
            for (int i = 0; i < 8; ++i) ga[i] = ntload4(gr0 + i * 32);
#pragma unroll
            for (int i = 0; i < 8; ++i) gbx[i] = ntload4(gr1 + i * 32);
            float p0 = 0.0f, p1 = 0.0f;
#pragma unroll
            for (int i = 0; i < 8; ++i) {
                const int d = i * 32 + oct * 4;
                const float4 h0v = *reinterpret_cast<const float4*>(&hgp[0][d]);
                const float4 h1v = *reinterpret_cast<const float4*>(&hgp[1][d]);
                const float4 vv = *reinterpret_cast<const float4*>(&gv_lds[d]);
                p0 = fmaf(ftanh_fast(ga[i].x + h0v.x), vv.x, p0);
                p0 = fmaf(ftanh_fast(ga[i].y + h0v.y), vv.y, p0);
                p0 = fmaf(ftanh_fast(ga[i].z + h0v.z), vv.z, p0);
                p0 = fmaf(ftanh_fast(ga[i].w + h0v.w), vv.w, p0);
                p1 = fmaf(ftanh_fast(gbx[i].x + h1v.x), vv.x, p1);
                p1 = fmaf(ftanh_fast(gbx[i].y + h1v.y), vv.y, p1);
                p1 = fmaf(ftanh_fast(gbx[i].z + h1v.z), vv.z, p1);
                p1 = fmaf(ftanh_fast(gbx[i].w + h1v.w), vv.w, p1);
            }
            p0 += __shfl_xor(p0, 1); p0 += __shfl_xor(p0, 2); p0 += __shfl_xor(p0, 4);
            p1 += __shfl_xor(p1, 1); p1 += __shfl_xor(p1, 2); p1 += __shfl_xor(p1, 4);
            if (oct == 0) {
                sc_arr[0][jg] = mask_lds[0][jg] ? -1e9f : p0 * 0.0625f;
                sc_arr[1][jg] = mask_lds[1][jg] ? -1e9f : p1 * 0.0625f;
            }
        }
        __syncthreads();
        // ---- phase 5: softmax (2 waves) ----
        if (wid < 2) {
            const int bt = wid;
            float s0 = sc_arr[bt][lane], s1 = sc_arr[bt][lane + 64];
            float m = fmaxf(s0, s1);
#pragma unroll
            for (int mk = 1; mk < 64; mk <<= 1) m = fmaxf(m, __shfl_xor(m, mk));
            float e0 = expf(s0 - m), e1 = expf(s1 - m);
            e_arr[bt][lane] = e0; e_arr[bt][lane + 64] = e1;
            float z = e0 + e1;
#pragma unroll
            for (int mk = 1; mk < 64; mk <<= 1) z += __shfl_xor(z, mk);
            if (lane == 0) Z_arr[bt] = z;
        }
        __syncthreads();
        // ---- phase 6: ctx partials (16 waves x 16 rows, all loads up front) ----
        {
            const int bt = wid & 1, sq = wid >> 1;   // sq 0..7, 16 s each
            const int d4 = lane * 4;
            const float* base = &encP[((size_t)((b0 + bt) * SS + sq * 16)) * 256 + d4];
            f32x4 pa[8], pb[8];
#pragma unroll
            for (int i = 0; i < 8; ++i) pa[i] = ld4(base + i * 256);
#pragma unroll
            for (int i = 0; i < 8; ++i) pb[i] = ld4(base + (8 + i) * 256);
            float ax = 0.0f, ay = 0.0f, az = 0.0f, aw = 0.0f;
#pragma unroll
            for (int i = 0; i < 8; ++i) {
                const float e = e_arr[bt][sq * 16 + i];
                ax = fmaf(pa[i].x, e, ax); ay = fmaf(pa[i].y, e, ay);
                az = fmaf(pa[i].z, e, az); aw = fmaf(pa[i].w, e, aw);
            }
#pragma unroll
            for (int i = 0; i < 8; ++i) {
                const float e = e_arr[bt][sq * 16 + 8 + i];
                ax = fmaf(pb[i].x, e, ax); ay = fmaf(pb[i].y, e, ay);
                az = fmaf(pb[i].z, e, az); aw = fmaf(pb[i].w, e, aw);
            }
            *reinterpret_cast<float4*>(&hp_half[sq][bt][d4]) = make_float4(ax, ay, az, aw);
        }
        __syncthreads();
        if (tid < 512) {
            const int bt = tid >> 8, d = tid & 255;
            float s = 0.0f;
#pragma unroll
            for (int k = 0; k < 8; ++k) s += hp_half[k][bt][d];
            hp_lds[bt][d] = hgp[bt][256 + d] + s * frcp(Z_arr[bt]);
        }
        __syncthreads();
        // ---- phase 7: ps scores (2 reps, deep ILP) ----
        {
            const float* pr0 = &p_ref[((size_t)((b0 + 0) * SS + jg)) * 256 + oct * 4];
            const float* pr1 = &p_ref[((size_t)((b0 + 1) * SS + jg)) * 256 + oct * 4];
            f32x4 ga[8], gbx[8];
#pragma unroll
            for (int i = 0; i < 8; ++i) ga[i] = ntload4(pr0 + i * 32);
#pragma unroll
            for (int i = 0; i < 8; ++i) gbx[i] = ntload4(pr1 + i * 32);
            float p0 = 0.0f, p1 = 0.0f;
#pragma unroll
            for (int i = 0; i < 8; ++i) {
                const int d = i * 32 + oct * 4;
                const float4 h0v = *reinterpret_cast<const float4*>(&hp_lds[0][d]);
                const float4 h1v = *reinterpret_cast<const float4*>(&hp_lds[1][d]);
                const float4 vv = *reinterpret_cast<const float4*>(&pv_lds[d]);
                p0 = fmaf(ftanh_fast(ga[i].x + h0v.x), vv.x, p0);
                p0 = fmaf(ftanh_fast(ga[i].y + h0v.y), vv.y, p0);
                p0 = fmaf(ftanh_fast(ga[i].z + h0v.z), vv.z, p0);
                p0 = fmaf(ftanh_fast(ga[i].w + h0v.w), vv.w, p0);
                p1 = fmaf(ftanh_fast(gbx[i].x + h1v.x), vv.x, p1);
                p1 = fmaf(ftanh_fast(gbx[i].y + h1v.y), vv.y, p1);
                p1 = fmaf(ftanh_fast(gbx[i].z + h1v.z), vv.z, p1);
                p1 = fmaf(ftanh_fast(gbx[i].w + h1v.w), vv.w, p1);
            }
            p0 += __shfl_xor(p0, 1); p0 += __shfl_xor(p0, 2); p0 += __shfl_xor(p0, 4);
            p1 += __shfl_xor(p1, 1); p1 += __shfl_xor(p1, 2); p1 += __shfl_xor(p1, 4);
            if (oct == 0) {
                sc_arr[0][jg] = mask_lds[0][jg] ? -1e9f : p0 * 0.0625f;
                sc_arr[1][jg] = mask_lds[1][jg] ? -1e9f : p1 * 0.0625f;
            }
        }
        __syncthreads();
        // ---- phase 8: logits write + argmax (first-max semantics) ----
        if (tid < 256) {
            const int bt = tid >> 7, s = tid & 127;
            out_logits[((size_t)((b0 + bt) * SS + t)) * SS + s] = sc_arr[bt][s];
        }
        if (wid < 2) {
            const int bt = wid;
            float v = sc_arr[bt][lane];
            int idx = lane;
            float v2 = sc_arr[bt][lane + 64];
            if (v2 > v) { v = v2; idx = lane + 64; }
#pragma unroll
            for (int mk = 1; mk < 64; mk <<= 1) {
                float ov = __shfl_xor(v, mk);
                int oi = __shfl_xor(idx, mk);
                if (ov > v || (ov == v && oi < idx)) { v = ov; idx = oi; }
            }
            if (lane == 0) {
                sel_arr[bt] = idx;
                mask_lds[bt][idx] = 1;
                out_ptrs[(size_t)(b0 + bt) * SS + t] = (float)idx;
            }
        }
        __syncthreads();
    }
}

// =====================================================================
// host launcher
// =====================================================================
extern "C" void kernel_launch(void* const* d_in, const int* in_sizes, int n_in,
                              void* d_out, int out_size, void* d_ws, size_t ws_size,
                              hipStream_t stream)
{
    (void)in_sizes; (void)n_in; (void)out_size; (void)ws_size;
    const float* x      = (const float*)d_in[0];
    const float* proj_W = (const float*)d_in[1];
    const float* proj_b = (const float*)d_in[2];
    const float* ln_g   = (const float*)d_in[3];
    const float* ln_b   = (const float*)d_in[4];
    const float* Wih_f  = (const float*)d_in[5];
    const float* Whh_f  = (const float*)d_in[6];
    const float* bih_f  = (const float*)d_in[7];
    const float* bhh_f  = (const float*)d_in[8];
    const float* Wih_b  = (const float*)d_in[9];
    const float* Whh_b  = (const float*)d_in[10];
    const float* bih_b  = (const float*)d_in[11];
    const float* bhh_b  = (const float*)d_in[12];
    const float* Wih_d  = (const float*)d_in[13];
    const float* Whh_d  = (const float*)d_in[14];
    const float* bih_d  = (const float*)d_in[15];
    const float* bhh_d  = (const float*)d_in[16];
    const float* hb_W   = (const float*)d_in[17];
    const float* hb_b   = (const float*)d_in[18];
    const float* cb_W   = (const float*)d_in[19];
    const float* cb_b   = (const float*)d_in[20];
    const float* gW1    = (const float*)d_in[21];
    const float* gW2    = (const float*)d_in[22];
    const float* gv     = (const float*)d_in[23];
    const float* pW1    = (const float*)d_in[24];
    const float* pW2    = (const float*)d_in[25];
    const float* pv     = (const float*)d_in[26];

    float* ws = (float*)d_ws;
    const size_t o_hT    = 0;
    const size_t o_cT    = 65536;
    const size_t o_h0    = 131072;
    const size_t o_c0    = 163840;
    const size_t o_pre0  = 196608;
    const size_t o_emb   = 0;
    const size_t o_xf    = 4194304;
    const size_t o_xb    = o_xf + 16777216;
    const size_t o_enc   = o_xb + 16777216;
    const size_t o_encW  = o_xf;
    const size_t o_gref  = o_xb;
    const size_t o_pref  = o_xb + 4194304;
    const size_t o_encP  = o_xb + 8388608;

    float* emb  = ws + o_emb;
    float* xf   = ws + o_xf;
    float* xb   = ws + o_xb;
    float* enc  = ws + o_enc;
    float* hT   = ws + o_hT;
    float* cT   = ws + o_cT;
    float* h0b  = ws + o_h0;
    float* c0b  = ws + o_c0;
    float* pre0 = ws + o_pre0;
    float* encW = ws + o_encW;
    float* gref = ws + o_gref;
    float* pref = ws + o_pref;
    float* encP = ws + o_encP;

    float* out_logits = (float*)d_out;
    float* out_ptrs   = out_logits + (size_t)BB * SS * SS;

    // 1. emb
    k_proj_ln<<<BB * SS, 256, 0, stream>>>(x, proj_W, proj_b, ln_g, ln_b, emb);
    // 2-3. xf / xb  (bias = bih + bhh)
    {
        dim3 g(128, 8);
        k_gemm_nt<<<g, 256, 0, stream>>>(emb, 256, Wih_f, xf, 16384, 1024, 256, bih_f, bhh_f, 0);
        k_gemm_nt<<<g, 256, 0, stream>>>(emb, 256, Wih_b, xb, 16384, 1024, 256, bih_b, bhh_b, 0);
    }
    // 4. LSTM both directions
    k_lstm<<<128, 512, 0, stream>>>(Whh_f, Whh_b, xf, xb, enc, hT, cT);
    // 5-6. h0 / c0
    {
        dim3 g(1, 2);
        k_gemm_nt<<<g, 256, 0, stream>>>(hT, 512, hb_W, h0b, 128, 256, 512, hb_b, nullptr, 1);
        k_gemm_nt<<<g, 256, 0, stream>>>(cT, 512, cb_W, c0b, 128, 256, 512, cb_b, nullptr, 1);
    }
    // 7-10. attention precomputes
    {
        dim3 g2(128, 2);
        k_gemm_nt<<<g2, 256, 0, stream>>>(enc, 512, gW1, gref, 16384, 256, 512, nullptr, nullptr, 0);
        k_gemm_nt<<<g2, 256, 0, stream>>>(enc, 512, pW1, pref, 16384, 256, 512, nullptr, nullptr, 0);
        dim3 g1(128, 8);
        k_gemm_nt<<<g1, 256, 0, stream>>>(enc, 512, Wih_d, encW, 16384, 1024, 512, bih_d, bhh_d, 0);
        k_gemm_nt<<<g2, 256, 0, stream>>>(enc, 512, pW2, encP, 16384, 256, 256, nullptr, nullptr, 0);
    }
    // 11. pre0 = mean_s encW
    k_meanw<<<BB, 256, 0, stream>>>(encW, pre0);
    // 12. decoder: 64 WGs x 2 batches x 1024 threads
    k_decoder<<<64, 1024, 0, stream>>>(Whh_d, gW2, pW2, gv, pv, gref, pref, encP, encW,
                                       pre0, h0b, c0b, out_logits, out_ptrs);
}

// Round 8
// 10704.294 us; speedup vs baseline: 1.3109x; 1.3109x over previous
//
#include <hip/hip_runtime.h>
#include <cstdint>
#include <cstddef>

#define DEVINL __device__ __forceinline__

typedef float f32x4 __attribute__((ext_vector_type(4)));

DEVINL f32x4 ntload4(const float* p) {
    return __builtin_nontemporal_load((const f32x4*)p);
}
DEVINL float ntload1(const float* p) {
    return __builtin_nontemporal_load(p);
}
DEVINL f32x4 ld4(const float* p) {
    return *reinterpret_cast<const f32x4*>(p);
}

// ---------- math helpers ----------
DEVINL float frcp(float x) { return __builtin_amdgcn_rcpf(x); }
DEVINL float ftanh_fast(float x) {
    float e = __expf(2.0f * x);
    return 1.0f - 2.0f * frcp(e + 1.0f);
}
DEVINL float sig_precise(float x) { return 1.0f / (1.0f + expf(-x)); }
DEVINL float tanh_precise(float x) { return tanhf(x); }

// ---------- sizes ----------
#define BB 128
#define SS 128
#define IND 16
#define DD 256
#define HH 256
#define H4 1024
#define H2 512

// =====================================================================
// K1: emb = LayerNorm(tanh(x @ proj_W.T + proj_b))   (one block per row)
// =====================================================================
__global__ __launch_bounds__(256) void k_proj_ln(
    const float* __restrict__ x, const float* __restrict__ projW,
    const float* __restrict__ projB, const float* __restrict__ ln_g,
    const float* __restrict__ ln_b, float* __restrict__ emb)
{
    __shared__ float Wl[256 * 17];
    __shared__ float xl[16];
    __shared__ float red[256];
    const int row = blockIdx.x;
    const int tid = threadIdx.x;
    for (int idx = tid; idx < 256 * 16; idx += 256) {
        int d = idx >> 4, i = idx & 15;
        Wl[d * 17 + i] = projW[idx];
    }
    if (tid < 16) xl[tid] = x[row * 16 + tid];
    __syncthreads();
    float acc = projB[tid];
#pragma unroll
    for (int i = 0; i < 16; ++i) acc = fmaf(Wl[tid * 17 + i], xl[i], acc);
    float v = tanh_precise(acc);
    red[tid] = v;
    __syncthreads();
    for (int s2 = 128; s2 > 0; s2 >>= 1) { if (tid < s2) red[tid] += red[tid + s2]; __syncthreads(); }
    float mean = red[0] * (1.0f / 256.0f);
    __syncthreads();
    float dlt = v - mean;
    red[tid] = dlt * dlt;
    __syncthreads();
    for (int s2 = 128; s2 > 0; s2 >>= 1) { if (tid < s2) red[tid] += red[tid + s2]; __syncthreads(); }
    float var = red[0] * (1.0f / 256.0f);
    float rs = 1.0f / sqrtf(var + 1e-5f);
    emb[(size_t)row * 256 + tid] = dlt * rs * ln_g[tid] + ln_b[tid];
}

// =====================================================================
// K2: generic fp32 GEMM-NT  C(MxN) = A(MxK,lda) * B(NxK)^T (+bias1+bias2)
// =====================================================================
__global__ __launch_bounds__(256) void k_gemm_nt(
    const float* __restrict__ A, int lda,
    const float* __restrict__ Bm,
    float* __restrict__ C,
    int M, int N, int K,
    const float* __restrict__ bias1, const float* __restrict__ bias2,
    int flags)
{
    __shared__ __align__(16) float As[16][132];
    __shared__ __align__(16) float Bs[16][132];
    const int tid = threadIdx.x;
    const int m0 = blockIdx.x * 128;
    const int n0 = blockIdx.y * 128;
    const int r = tid >> 1, half = tid & 1;
    const int tm = tid & 15, tn = tid >> 4;
    float acc[8][8];
#pragma unroll
    for (int i = 0; i < 8; ++i)
#pragma unroll
        for (int j = 0; j < 8; ++j) acc[i][j] = 0.0f;

    for (int k0 = 0; k0 < K; k0 += 16) {
        const float4* pa = reinterpret_cast<const float4*>(&A[(size_t)(m0 + r) * lda + k0 + half * 8]);
        float4 a0 = pa[0], a1 = pa[1];
        const float4* pb = reinterpret_cast<const float4*>(&Bm[(size_t)(n0 + r) * K + k0 + half * 8]);
        float4 b0 = pb[0], b1 = pb[1];
        __syncthreads();
        const int kb = half * 8;
        As[kb + 0][r] = a0.x; As[kb + 1][r] = a0.y; As[kb + 2][r] = a0.z; As[kb + 3][r] = a0.w;
        As[kb + 4][r] = a1.x; As[kb + 5][r] = a1.y; As[kb + 6][r] = a1.z; As[kb + 7][r] = a1.w;
        Bs[kb + 0][r] = b0.x; Bs[kb + 1][r] = b0.y; Bs[kb + 2][r] = b0.z; Bs[kb + 3][r] = b0.w;
        Bs[kb + 4][r] = b1.x; Bs[kb + 5][r] = b1.y; Bs[kb + 6][r] = b1.z; Bs[kb + 7][r] = b1.w;
        __syncthreads();
#pragma unroll
        for (int kk = 0; kk < 16; ++kk) {
            const float4 xa0 = *reinterpret_cast<const float4*>(&As[kk][tm * 8]);
            const float4 xa1 = *reinterpret_cast<const float4*>(&As[kk][tm * 8 + 4]);
            const float4 xb0 = *reinterpret_cast<const float4*>(&Bs[kk][tn * 8]);
            const float4 xb1 = *reinterpret_cast<const float4*>(&Bs[kk][tn * 8 + 4]);
            const float av[8] = {xa0.x, xa0.y, xa0.z, xa0.w, xa1.x, xa1.y, xa1.z, xa1.w};
            const float bv[8] = {xb0.x, xb0.y, xb0.z, xb0.w, xb1.x, xb1.y, xb1.z, xb1.w};
#pragma unroll
            for (int i = 0; i < 8; ++i)
#pragma unroll
                for (int j = 0; j < 8; ++j) acc[i][j] = fmaf(av[i], bv[j], acc[i][j]);
        }
    }
    const int nb = n0 + tn * 8;
    float bias[8];
#pragma unroll
    for (int j = 0; j < 8; ++j) {
        float bbv = 0.0f;
        if (bias1) bbv += bias1[nb + j];
        if (bias2) bbv += bias2[nb + j];
        bias[j] = bbv;
    }
#pragma unroll
    for (int i = 0; i < 8; ++i) {
        const size_t m = (size_t)(m0 + tm * 8 + i);
        float o[8];
#pragma unroll
        for (int j = 0; j < 8; ++j) {
            float vv = acc[i][j] + bias[j];
            if (flags & 1) vv = tanh_precise(vv);
            o[j] = vv;
        }
        float4* pc = reinterpret_cast<float4*>(&C[m * N + nb]);
        pc[0] = make_float4(o[0], o[1], o[2], o[3]);
        pc[1] = make_float4(o[4], o[5], o[6], o[7]);
    }
}

// =====================================================================
// K3: bidirectional LSTM (explicit prefetch stream)
// grid 128 = 2 dirs * 64 groups; 512 threads; 2 batches/WG.
// =====================================================================
__global__ __launch_bounds__(512, 2) void k_lstm(
    const float* __restrict__ Whh_f, const float* __restrict__ Whh_b,
    const float* __restrict__ xf, const float* __restrict__ xb,
    float* __restrict__ enc, float* __restrict__ hT, float* __restrict__ cT)
{
    const int wg = blockIdx.x;       // 0..127
    const int dir = wg >> 6;
    const int grp = wg & 63;
    const int bb0 = grp * 2;
    const float* W = dir ? Whh_b : Whh_f;
    const float* xin = dir ? xb : xf;
    const int tid = threadIdx.x;
    const int oct = tid & 7, jg = tid >> 3;   // jg 0..63
    const int gc = tid & 255, gb = tid >> 8;

    __shared__ __align__(16) float h_lds[2][256];
    __shared__ float pre_lds[2][1024];

    for (int i = tid; i < 2 * 256; i += 512) (&h_lds[0][0])[i] = 0.0f;
    float c_reg = 0.0f;
    __syncthreads();

    for (int t = 0; t < SS; ++t) {
        const int st = dir ? (SS - 1 - t) : t;
        float hreg[2][32];
#pragma unroll
        for (int bsel = 0; bsel < 2; ++bsel) {
#pragma unroll
            for (int i = 0; i < 8; ++i) {
                float4 v = *reinterpret_cast<const float4*>(&h_lds[bsel][i * 32 + oct * 4]);
                hreg[bsel][i * 4 + 0] = v.x; hreg[bsel][i * 4 + 1] = v.y;
                hreg[bsel][i * 4 + 2] = v.z; hreg[bsel][i * 4 + 3] = v.w;
            }
        }
        // W pass: 16 q-rounds of 64 rows, 1-ahead prefetch
        float4 wb[8];
        {
            const float* bp = &W[(size_t)jg * 256 + oct * 4];
#pragma unroll
            for (int i = 0; i < 8; ++i) wb[i] = *reinterpret_cast<const float4*>(bp + i * 32);
        }
        for (int q = 0; q < 16; ++q) {
            float4 wn[8];
            if (q < 15) {
                const float* bp = &W[(size_t)((q + 1) * 64 + jg) * 256 + oct * 4];
#pragma unroll
                for (int i = 0; i < 8; ++i) wn[i] = *reinterpret_cast<const float4*>(bp + i * 32);
            }
            float a0 = 0.0f, a1 = 0.0f;
#pragma unroll
            for (int i = 0; i < 8; ++i) {
                a0 = fmaf(wb[i].x, hreg[0][i * 4 + 0], a0);
                a0 = fmaf(wb[i].y, hreg[0][i * 4 + 1], a0);
                a0 = fmaf(wb[i].z, hreg[0][i * 4 + 2], a0);
                a0 = fmaf(wb[i].w, hreg[0][i * 4 + 3], a0);
                a1 = fmaf(wb[i].x, hreg[1][i * 4 + 0], a1);
                a1 = fmaf(wb[i].y, hreg[1][i * 4 + 1], a1);
                a1 = fmaf(wb[i].z, hreg[1][i * 4 + 2], a1);
                a1 = fmaf(wb[i].w, hreg[1][i * 4 + 3], a1);
            }
            a0 += __shfl_xor(a0, 1); a0 += __shfl_xor(a0, 2); a0 += __shfl_xor(a0, 4);
            a1 += __shfl_xor(a1, 1); a1 += __shfl_xor(a1, 2); a1 += __shfl_xor(a1, 4);
            if (oct == 0) {
                const int row = q * 64 + jg;
                pre_lds[0][row] = a0; pre_lds[1][row] = a1;
            }
#pragma unroll
            for (int i = 0; i < 8; ++i) wb[i] = wn[i];
        }
        __syncthreads();
        {
            const float* xrow = &xin[((size_t)(bb0 + gb) * SS + st) * 1024];
            float pi = pre_lds[gb][gc]       + ntload1(&xrow[gc]);
            float pf = pre_lds[gb][256 + gc] + ntload1(&xrow[256 + gc]);
            float pg = pre_lds[gb][512 + gc] + ntload1(&xrow[512 + gc]);
            float po = pre_lds[gb][768 + gc] + ntload1(&xrow[768 + gc]);
            float ig = sig_precise(pi), fg = sig_precise(pf);
            float gg = tanh_precise(pg), og = sig_precise(po);
            float cn = fmaf(fg, c_reg, ig * gg);
            float hn = og * tanh_precise(cn);
            c_reg = cn;
            h_lds[gb][gc] = hn;
            enc[((size_t)(bb0 + gb) * SS + st) * 512 + dir * 256 + gc] = hn;
            if (t == SS - 1) {
                hT[(size_t)(bb0 + gb) * 512 + dir * 256 + gc] = hn;
                cT[(size_t)(bb0 + gb) * 512 + dir * 256 + gc] = cn;
            }
        }
        __syncthreads();
    }
}

// =====================================================================
// K5: pre0[b][j] = mean_s encW[b][s][j]
// =====================================================================
__global__ __launch_bounds__(256) void k_meanw(const float* __restrict__ encW, float* __restrict__ pre0)
{
    const int b = blockIdx.x;
    const int tid = threadIdx.x;
    const float4* base = reinterpret_cast<const float4*>(&encW[(size_t)b * SS * 1024]);
    float sx = 0.0f, sy = 0.0f, sz = 0.0f, sw = 0.0f;
    for (int s = 0; s < SS; ++s) {
        float4 v = base[s * 256 + tid];
        sx += v.x; sy += v.y; sz += v.z; sw += v.w;
    }
    float4* out = reinterpret_cast<float4*>(&pre0[(size_t)b * 1024]);
    out[tid] = make_float4(sx * (1.0f / 128.0f), sy * (1.0f / 128.0f), sz * (1.0f / 128.0f), sw * (1.0f / 128.0f));
}

// =====================================================================
// K6: pointer decoder, 64 WGs x 2 batches, 512 threads, 128 steps.
// R6 structure (deep-ILP branchless phases, 1-ahead prefetch) with ALL
// loads PLAIN (no nontemporal): refs/encP/encW are L2/L3-resident --
// the nt hints were streaming 42 MB/step straight from HBM (R5-R7
// FETCH_SIZE == per-step nt footprint exactly).
// =====================================================================
__global__ __launch_bounds__(512, 2) void k_decoder(
    const float* __restrict__ Whh_d,
    const float* __restrict__ gW2, const float* __restrict__ pW2,
    const float* __restrict__ gv, const float* __restrict__ pv,
    const float* __restrict__ g_ref, const float* __restrict__ p_ref,
    const float* __restrict__ encP, const float* __restrict__ encW,
    const float* __restrict__ pre0, const float* __restrict__ h0,
    const float* __restrict__ c0,
    float* __restrict__ out_logits, float* __restrict__ out_ptrs)
{
    const int b0 = blockIdx.x * 2;
    const int tid = threadIdx.x;
    const int oct = tid & 7, jg = tid >> 3;   // jg 0..63
    const int wid = tid >> 6, lane = tid & 63;

    __shared__ __align__(16) float h_lds[2][256];
    __shared__ float c_lds[2][256];
    __shared__ float pre_lds[2][1024];
    __shared__ float row_lds[2][1024];
    __shared__ __align__(16) float hgp[2][512];   // [.,0..255]=hg, [.,256..511]=hp1
    __shared__ __align__(16) float hp_lds[2][256];
    __shared__ __align__(16) float gv_lds[256];
    __shared__ __align__(16) float pv_lds[256];
    __shared__ float sc_arr[2][128];
    __shared__ float e_arr[2][128];
    __shared__ __align__(16) float hp_half[4][2][256];
    __shared__ int mask_lds[2][128];
    __shared__ float Z_arr[2];
    __shared__ int sel_arr[2];

    if (tid < 256) {
        gv_lds[tid] = gv[tid];
        pv_lds[tid] = pv[tid];
#pragma unroll
        for (int bt = 0; bt < 2; ++bt) {
            h_lds[bt][tid] = h0[(size_t)(b0 + bt) * 256 + tid];
            c_lds[bt][tid] = c0[(size_t)(b0 + bt) * 256 + tid];
        }
    }
    if (tid < 128) { mask_lds[0][tid] = 0; mask_lds[1][tid] = 0; }
    if (tid < 2) sel_arr[tid] = -1;
    __syncthreads();

    for (int t = 0; t < SS; ++t) {
        // ---- stage xt rows (encW[sel] or pre0); h_{t-1} -> regs ----
#pragma unroll
        for (int rep = 0; rep < 4; ++rep) {
            const int idx = tid + rep * 512;
            const int bt = idx >> 10, j = idx & 1023;
            const int sel = sel_arr[bt];
            const float* src = (sel < 0) ? &pre0[(size_t)(b0 + bt) * 1024]
                                         : &encW[((size_t)((b0 + bt) * SS + sel)) * 1024];
            row_lds[bt][j] = src[j];
        }
        float hreg[2][32];
#pragma unroll
        for (int bt = 0; bt < 2; ++bt) {
#pragma unroll
            for (int i = 0; i < 8; ++i) {
                float4 v = *reinterpret_cast<const float4*>(&h_lds[bt][i * 32 + oct * 4]);
                hreg[bt][i * 4 + 0] = v.x; hreg[bt][i * 4 + 1] = v.y;
                hreg[bt][i * 4 + 2] = v.z; hreg[bt][i * 4 + 3] = v.w;
            }
        }
        __syncthreads();
        // ---- phase 1: pre = row + Whh_d @ h (1-ahead prefetch) ----
        {
            float4 wb[8];
            {
                const float* bp = &Whh_d[(size_t)jg * 256 + oct * 4];
#pragma unroll
                for (int i = 0; i < 8; ++i) wb[i] = *reinterpret_cast<const float4*>(bp + i * 32);
            }
            for (int q = 0; q < 16; ++q) {
                float4 wn[8];
                if (q < 15) {
                    const float* bp = &Whh_d[(size_t)((q + 1) * 64 + jg) * 256 + oct * 4];
#pragma unroll
                    for (int i = 0; i < 8; ++i) wn[i] = *reinterpret_cast<const float4*>(bp + i * 32);
                }
                float a0 = 0.0f, a1 = 0.0f;
#pragma unroll
                for (int i = 0; i < 8; ++i) {
                    const float w4[4] = {wb[i].x, wb[i].y, wb[i].z, wb[i].w};
#pragma unroll
                    for (int c = 0; c < 4; ++c) {
                        const int k = i * 4 + c;
                        a0 = fmaf(w4[c], hreg[0][k], a0);
                        a1 = fmaf(w4[c], hreg[1][k], a1);
                    }
                }
                a0 += __shfl_xor(a0, 1); a0 += __shfl_xor(a0, 2); a0 += __shfl_xor(a0, 4);
                a1 += __shfl_xor(a1, 1); a1 += __shfl_xor(a1, 2); a1 += __shfl_xor(a1, 4);
                if (oct == 0) {
                    const int row = q * 64 + jg;
                    pre_lds[0][row] = a0 + row_lds[0][row];
                    pre_lds[1][row] = a1 + row_lds[1][row];
                }
#pragma unroll
                for (int i = 0; i < 8; ++i) wb[i] = wn[i];
            }
        }
        __syncthreads();
        // ---- phase 2: gates (512 tasks, 1 per thread) ----
        {
            const int bt = tid >> 8, ch = tid & 255;
            float pi = pre_lds[bt][ch],        pf = pre_lds[bt][256 + ch];
            float pg = pre_lds[bt][512 + ch],  po = pre_lds[bt][768 + ch];
            float ig = sig_precise(pi), fg = sig_precise(pf);
            float gg = tanh_precise(pg), og = sig_precise(po);
            float cn = fmaf(fg, c_lds[bt][ch], ig * gg);
            float hn = og * tanh_precise(cn);
            c_lds[bt][ch] = cn;
            h_lds[bt][ch] = hn;
        }
        __syncthreads();
        // reload new h slices
        float hreg2[2][32];
#pragma unroll
        for (int bt = 0; bt < 2; ++bt) {
#pragma unroll
            for (int i = 0; i < 8; ++i) {
                float4 v = *reinterpret_cast<const float4*>(&h_lds[bt][i * 32 + oct * 4]);
                hreg2[bt][i * 4 + 0] = v.x; hreg2[bt][i * 4 + 1] = v.y;
                hreg2[bt][i * 4 + 2] = v.z; hreg2[bt][i * 4 + 3] = v.w;
            }
        }
        // ---- phase 3: hg = h@gW2.T (rows 0..255), hp1 = h@pW2.T (256..511) ----
        {
            float4 wb[8];
            {
                const float* bp = &gW2[(size_t)jg * 256 + oct * 4];
#pragma unroll
                for (int i = 0; i < 8; ++i) wb[i] = *reinterpret_cast<const float4*>(bp + i * 32);
            }
            for (int q = 0; q < 8; ++q) {
                float4 wn[8];
                if (q < 7) {
                    const int r2 = (q + 1) * 64 + jg;
                    const float* src = (r2 < 256) ? &gW2[(size_t)r2 * 256] : &pW2[(size_t)(r2 - 256) * 256];
#pragma unroll
                    for (int i = 0; i < 8; ++i) wn[i] = *reinterpret_cast<const float4*>(src + oct * 4 + i * 32);
                }
                float a0 = 0.0f, a1 = 0.0f;
#pragma unroll
                for (int i = 0; i < 8; ++i) {
                    const float w4[4] = {wb[i].x, wb[i].y, wb[i].z, wb[i].w};
#pragma unroll
                    for (int c = 0; c < 4; ++c) {
                        const int k = i * 4 + c;
                        a0 = fmaf(w4[c], hreg2[0][k], a0);
                        a1 = fmaf(w4[c], hreg2[1][k], a1);
                    }
                }
                a0 += __shfl_xor(a0, 1); a0 += __shfl_xor(a0, 2); a0 += __shfl_xor(a0, 4);
                a1 += __shfl_xor(a1, 1); a1 += __shfl_xor(a1, 2); a1 += __shfl_xor(a1, 4);
                if (oct == 0) {
                    const int row = q * 64 + jg;
                    hgp[0][row] = a0; hgp[1][row] = a1;
                }
#pragma unroll
                for (int i = 0; i < 8; ++i) wb[i] = wn[i];
            }
        }
        __syncthreads();
        // ---- phase 4: gs scores, branchless, 1-ahead prefetch (plain loads) ----
        {
            f32x4 gb[8];
            {
                const float* gr = &g_ref[((size_t)(b0 * SS + jg)) * 256 + oct * 4];
#pragma unroll
                for (int i = 0; i < 8; ++i) gb[i] = ld4(gr + i * 32);
            }
#pragma unroll
            for (int rep = 0; rep < 4; ++rep) {
                const int bt = rep & 1;
                const int r = jg + 64 * (rep >> 1);
                f32x4 gn[8];
                if (rep < 3) {
                    const int btn = (rep + 1) & 1, rn = jg + 64 * ((rep + 1) >> 1);
                    const float* gr = &g_ref[((size_t)((b0 + btn) * SS + rn)) * 256 + oct * 4];
#pragma unroll
                    for (int i = 0; i < 8; ++i) gn[i] = ld4(gr + i * 32);
                }
                float part = 0.0f;
#pragma unroll
                for (int i = 0; i < 8; ++i) {
                    const int d = i * 32 + oct * 4;
                    const float4 hh = *reinterpret_cast<const float4*>(&hgp[bt][d]);
                    const float4 vv = *reinterpret_cast<const float4*>(&gv_lds[d]);
                    part = fmaf(ftanh_fast(gb[i].x + hh.x), vv.x, part);
                    part = fmaf(ftanh_fast(gb[i].y + hh.y), vv.y, part);
                    part = fmaf(ftanh_fast(gb[i].z + hh.z), vv.z, part);
                    part = fmaf(ftanh_fast(gb[i].w + hh.w), vv.w, part);
                }
                part += __shfl_xor(part, 1); part += __shfl_xor(part, 2); part += __shfl_xor(part, 4);
                if (oct == 0) sc_arr[bt][r] = mask_lds[bt][r] ? -1e9f : part * 0.0625f;
#pragma unroll
                for (int i = 0; i < 8; ++i) gb[i] = gn[i];
            }
        }
        __syncthreads();
        // ---- phase 5: softmax (2 waves) ----
        if (wid < 2) {
            const int bt = wid;
            float s0 = sc_arr[bt][lane], s1 = sc_arr[bt][lane + 64];
            float m = fmaxf(s0, s1);
#pragma unroll
            for (int mk = 1; mk < 64; mk <<= 1) m = fmaxf(m, __shfl_xor(m, mk));
            float e0 = expf(s0 - m), e1 = expf(s1 - m);
            e_arr[bt][lane] = e0; e_arr[bt][lane + 64] = e1;
            float z = e0 + e1;
#pragma unroll
            for (int mk = 1; mk < 64; mk <<= 1) z += __shfl_xor(z, mk);
            if (lane == 0) Z_arr[bt] = z;
        }
        __syncthreads();
        // ---- phase 6: ctx partials, branchless (masked e==0), pipelined ----
        {
            const int bt = wid & 1, sq = wid >> 1;   // sq 0..3, 32 s each
            const int d4 = lane * 4;
            const float* base = &encP[((size_t)((b0 + bt) * SS + sq * 32)) * 256 + d4];
            float ax = 0.0f, ay = 0.0f, az = 0.0f, aw = 0.0f;
            f32x4 pb[8];
#pragma unroll
            for (int i = 0; i < 8; ++i) pb[i] = ld4(base + i * 256);
#pragma unroll
            for (int g = 0; g < 4; ++g) {
                f32x4 pn[8];
                if (g < 3) {
#pragma unroll
                    for (int i = 0; i < 8; ++i) pn[i] = ld4(base + (g + 1) * 8 * 256 + i * 256);
                }
#pragma unroll
                for (int i = 0; i < 8; ++i) {
                    const float e = e_arr[bt][sq * 32 + g * 8 + i];
                    ax = fmaf(pb[i].x, e, ax); ay = fmaf(pb[i].y, e, ay);
                    az = fmaf(pb[i].z, e, az); aw = fmaf(pb[i].w, e, aw);
                }
#pragma unroll
                for (int i = 0; i < 8; ++i) pb[i] = pn[i];
            }
            *reinterpret_cast<float4*>(&hp_half[sq][bt][d4]) = make_float4(ax, ay, az, aw);
        }
        __syncthreads();
        {
            const int bt = tid >> 8, d = tid & 255;
            hp_lds[bt][d] = hgp[bt][256 + d] +
                            (hp_half[0][bt][d] + hp_half[1][bt][d] +
                             hp_half[2][bt][d] + hp_half[3][bt][d]) * frcp(Z_arr[bt]);
        }
        __syncthreads();
        // ---- phase 7: ps scores, branchless, 1-ahead prefetch (plain loads) ----
        {
            f32x4 gb[8];
            {
                const float* pr = &p_ref[((size_t)(b0 * SS + jg)) * 256 + oct * 4];
#pragma unroll
                for (int i = 0; i < 8; ++i) gb[i] = ld4(pr + i * 32);
            }
#pragma unroll
            for (int rep = 0; rep < 4; ++rep) {
                const int bt = rep & 1;
                const int r = jg + 64 * (rep >> 1);
                f32x4 gn[8];
                if (rep < 3) {
                    const int btn = (rep + 1) & 1, rn = jg + 64 * ((rep + 1) >> 1);
                    const float* pr = &p_ref[((size_t)((b0 + btn) * SS + rn)) * 256 + oct * 4];
#pragma unroll
                    for (int i = 0; i < 8; ++i) gn[i] = ld4(pr + i * 32);
                }
                float part = 0.0f;
#pragma unroll
                for (int i = 0; i < 8; ++i) {
                    const int d = i * 32 + oct * 4;
                    const float4 hh = *reinterpret_cast<const float4*>(&hp_lds[bt][d]);
                    const float4 vv = *reinterpret_cast<const float4*>(&pv_lds[d]);
                    part = fmaf(ftanh_fast(gb[i].x + hh.x), vv.x, part);
                    part = fmaf(ftanh_fast(gb[i].y + hh.y), vv.y, part);
                    part = fmaf(ftanh_fast(gb[i].z + hh.z), vv.z, part);
                    part = fmaf(ftanh_fast(gb[i].w + hh.w), vv.w, part);
                }
                part += __shfl_xor(part, 1); part += __shfl_xor(part, 2); part += __shfl_xor(part, 4);
                if (oct == 0) sc_arr[bt][r] = mask_lds[bt][r] ? -1e9f : part * 0.0625f;
#pragma unroll
                for (int i = 0; i < 8; ++i) gb[i] = gn[i];
            }
        }
        __syncthreads();
        // ---- phase 8: logits write + argmax (first-max semantics) ----
        if (tid < 256) {
            const int bt = tid >> 7, s = tid & 127;
            out_logits[((size_t)((b0 + bt) * SS + t)) * SS + s] = sc_arr[bt][s];
        }
        if (wid < 2) {
            const int bt = wid;
            float v = sc_arr[bt][lane];
            int idx = lane;
            float v2 = sc_arr[bt][lane + 64];
            if (v2 > v) { v = v2; idx = lane + 64; }
#pragma unroll
            for (int mk = 1; mk < 64; mk <<= 1) {
                float ov = __shfl_xor(v, mk);
                int oi = __shfl_xor(idx, mk);
                if (ov > v || (ov == v && oi < idx)) { v = ov; idx = oi; }
            }
            if (lane == 0) {
                sel_arr[bt] = idx;
                mask_lds[bt][idx] = 1;
                out_ptrs[(size_t)(b0 + bt) * SS + t] = (float)idx;
            }
        }
        __syncthreads();
    }
}

// =====================================================================
// host launcher
// =====================================================================
extern "C" void kernel_launch(void* const* d_in, const int* in_sizes, int n_in,
                              void* d_out, int out_size, void* d_ws, size_t ws_size,
                              hipStream_t stream)
{
    (void)in_sizes; (void)n_in; (void)out_size; (void)ws_size;
    const float* x      = (const float*)d_in[0];
    const float* proj_W = (const float*)d_in[1];
    const float* proj_b = (const float*)d_in[2];
    const float* ln_g   = (const float*)d_in[3];
    const float* ln_b   = (const float*)d_in[4];
    const float* Wih_f  = (const float*)d_in[5];
    const float* Whh_f  = (const float*)d_in[6];
    const float* bih_f  = (const float*)d_in[7];
    const float* bhh_f  = (const float*)d_in[8];
    const float* Wih_b  = (const float*)d_in[9];
    const float* Whh_b  = (const float*)d_in[10];
    const float* bih_b  = (const float*)d_in[11];
    const float* bhh_b  = (const float*)d_in[12];
    const float* Wih_d  = (const float*)d_in[13];
    const float* Whh_d  = (const float*)d_in[14];
    const float* bih_d  = (const float*)d_in[15];
    const float* bhh_d  = (const float*)d_in[16];
    const float* hb_W   = (const float*)d_in[17];
    const float* hb_b   = (const float*)d_in[18];
    const float* cb_W   = (const float*)d_in[19];
    const float* cb_b   = (const float*)d_in[20];
    const float* gW1    = (const float*)d_in[21];
    const float* gW2    = (const float*)d_in[22];
    const float* gv     = (const float*)d_in[23];
    const float* pW1    = (const float*)d_in[24];
    const float* pW2    = (const float*)d_in[25];
    const float* pv     = (const float*)d_in[26];

    float* ws = (float*)d_ws;
    const size_t o_hT    = 0;
    const size_t o_cT    = 65536;
    const size_t o_h0    = 131072;
    const size_t o_c0    = 163840;
    const size_t o_pre0  = 196608;
    const size_t o_emb   = 0;
    const size_t o_xf    = 4194304;
    const size_t o_xb    = o_xf + 16777216;
    const size_t o_enc   = o_xb + 16777216;
    const size_t o_encW  = o_xf;
    const size_t o_gref  = o_xb;
    const size_t o_pref  = o_xb + 4194304;
    const size_t o_encP  = o_xb + 8388608;

    float* emb  = ws + o_emb;
    float* xf   = ws + o_xf;
    float* xb   = ws + o_xb;
    float* enc  = ws + o_enc;
    float* hT   = ws + o_hT;
    float* cT   = ws + o_cT;
    float* h0b  = ws + o_h0;
    float* c0b  = ws + o_c0;
    float* pre0 = ws + o_pre0;
    float* encW = ws + o_encW;
    float* gref = ws + o_gref;
    float* pref = ws + o_pref;
    float* encP = ws + o_encP;

    float* out_logits = (float*)d_out;
    float* out_ptrs   = out_logits + (size_t)BB * SS * SS;

    // 1. emb
    k_proj_ln<<<BB * SS, 256, 0, stream>>>(x, proj_W, proj_b, ln_g, ln_b, emb);
    // 2-3. xf / xb  (bias = bih + bhh)
    {
        dim3 g(128, 8);
        k_gemm_nt<<<g, 256, 0, stream>>>(emb, 256, Wih_f, xf, 16384, 1024, 256, bih_f, bhh_f, 0);
        k_gemm_nt<<<g, 256, 0, stream>>>(emb, 256, Wih_b, xb, 16384, 1024, 256, bih_b, bhh_b, 0);
    }
    // 4. LSTM both directions
    k_lstm<<<128, 512, 0, stream>>>(Whh_f, Whh_b, xf, xb, enc, hT, cT);
    // 5-6. h0 / c0
    {
        dim3 g(1, 2);
        k_gemm_nt<<<g, 256, 0, stream>>>(hT, 512, hb_W, h0b, 128, 256, 512, hb_b, nullptr, 1);
        k_gemm_nt<<<g, 256, 0, stream>>>(cT, 512, cb_W, c0b, 128, 256, 512, cb_b, nullptr, 1);
    }
    // 7-10. attention precomputes
    {
        dim3 g2(128, 2);
        k_gemm_nt<<<g2, 256, 0, stream>>>(enc, 512, gW1, gref, 16384, 256, 512, nullptr, nullptr, 0);
        k_gemm_nt<<<g2, 256, 0, stream>>>(enc, 512, pW1, pref, 16384, 256, 512, nullptr, nullptr, 0);
        dim3 g1(128, 8);
        k_gemm_nt<<<g1, 256, 0, stream>>>(enc, 512, Wih_d, encW, 16384, 1024, 512, bih_d, bhh_d, 0);
        k_gemm_nt<<<g2, 256, 0, stream>>>(enc, 512, pW2, encP, 16384, 256, 256, nullptr, nullptr, 0);
    }
    // 11. pre0 = mean_s encW
    k_meanw<<<BB, 256, 0, stream>>>(encW, pre0);
    // 12. decoder: 64 WGs x 2 batches, plain (cacheable) ref loads
    k_decoder<<<64, 512, 0, stream>>>(Whh_d, gW2, pW2, gv, pv, gref, pref, encP, encW,
                                      pre0, h0b, c0b, out_logits, out_ptrs);
}

// Round 9
// 6640.617 us; speedup vs baseline: 2.1131x; 1.6119x over previous
//
#include <hip/hip_runtime.h>
#include <cstdint>
#include <cstddef>

#define DEVINL __device__ __forceinline__

typedef float f32x4 __attribute__((ext_vector_type(4)));

DEVINL float ntload1(const float* p) {
    return __builtin_nontemporal_load(p);
}
DEVINL f32x4 ld4(const float* p) {
    return *reinterpret_cast<const f32x4*>(p);
}

// ---------- math helpers ----------
DEVINL float frcp(float x) { return __builtin_amdgcn_rcpf(x); }
DEVINL float ftanh_fast(float x) {
    float e = __expf(2.0f * x);
    return 1.0f - 2.0f * frcp(e + 1.0f);
}
DEVINL float sig_precise(float x) { return 1.0f / (1.0f + expf(-x)); }
DEVINL float tanh_precise(float x) { return tanhf(x); }

// ---------- sizes ----------
#define BB 128
#define SS 128
#define IND 16
#define DD 256
#define HH 256
#define H4 1024
#define H2 512

// =====================================================================
// K1: emb = LayerNorm(tanh(x @ proj_W.T + proj_b))   (one block per row)
// =====================================================================
__global__ __launch_bounds__(256) void k_proj_ln(
    const float* __restrict__ x, const float* __restrict__ projW,
    const float* __restrict__ projB, const float* __restrict__ ln_g,
    const float* __restrict__ ln_b, float* __restrict__ emb)
{
    __shared__ float Wl[256 * 17];
    __shared__ float xl[16];
    __shared__ float red[256];
    const int row = blockIdx.x;
    const int tid = threadIdx.x;
    for (int idx = tid; idx < 256 * 16; idx += 256) {
        int d = idx >> 4, i = idx & 15;
        Wl[d * 17 + i] = projW[idx];
    }
    if (tid < 16) xl[tid] = x[row * 16 + tid];
    __syncthreads();
    float acc = projB[tid];
#pragma unroll
    for (int i = 0; i < 16; ++i) acc = fmaf(Wl[tid * 17 + i], xl[i], acc);
    float v = tanh_precise(acc);
    red[tid] = v;
    __syncthreads();
    for (int s2 = 128; s2 > 0; s2 >>= 1) { if (tid < s2) red[tid] += red[tid + s2]; __syncthreads(); }
    float mean = red[0] * (1.0f / 256.0f);
    __syncthreads();
    float dlt = v - mean;
    red[tid] = dlt * dlt;
    __syncthreads();
    for (int s2 = 128; s2 > 0; s2 >>= 1) { if (tid < s2) red[tid] += red[tid + s2]; __syncthreads(); }
    float var = red[0] * (1.0f / 256.0f);
    float rs = 1.0f / sqrtf(var + 1e-5f);
    emb[(size_t)row * 256 + tid] = dlt * rs * ln_g[tid] + ln_b[tid];
}

// =====================================================================
// K2: generic fp32 GEMM-NT  C(MxN) = A(MxK,lda) * B(NxK)^T (+bias1+bias2)
// =====================================================================
__global__ __launch_bounds__(256) void k_gemm_nt(
    const float* __restrict__ A, int lda,
    const float* __restrict__ Bm,
    float* __restrict__ C,
    int M, int N, int K,
    const float* __restrict__ bias1, const float* __restrict__ bias2,
    int flags)
{
    __shared__ __align__(16) float As[16][132];
    __shared__ __align__(16) float Bs[16][132];
    const int tid = threadIdx.x;
    const int m0 = blockIdx.x * 128;
    const int n0 = blockIdx.y * 128;
    const int r = tid >> 1, half = tid & 1;
    const int tm = tid & 15, tn = tid >> 4;
    float acc[8][8];
#pragma unroll
    for (int i = 0; i < 8; ++i)
#pragma unroll
        for (int j = 0; j < 8; ++j) acc[i][j] = 0.0f;

    for (int k0 = 0; k0 < K; k0 += 16) {
        const float4* pa = reinterpret_cast<const float4*>(&A[(size_t)(m0 + r) * lda + k0 + half * 8]);
        float4 a0 = pa[0], a1 = pa[1];
        const float4* pb = reinterpret_cast<const float4*>(&Bm[(size_t)(n0 + r) * K + k0 + half * 8]);
        float4 b0 = pb[0], b1 = pb[1];
        __syncthreads();
        const int kb = half * 8;
        As[kb + 0][r] = a0.x; As[kb + 1][r] = a0.y; As[kb + 2][r] = a0.z; As[kb + 3][r] = a0.w;
        As[kb + 4][r] = a1.x; As[kb + 5][r] = a1.y; As[kb + 6][r] = a1.z; As[kb + 7][r] = a1.w;
        Bs[kb + 0][r] = b0.x; Bs[kb + 1][r] = b0.y; Bs[kb + 2][r] = b0.z; Bs[kb + 3][r] = b0.w;
        Bs[kb + 4][r] = b1.x; Bs[kb + 5][r] = b1.y; Bs[kb + 6][r] = b1.z; Bs[kb + 7][r] = b1.w;
        __syncthreads();
#pragma unroll
        for (int kk = 0; kk < 16; ++kk) {
            const float4 xa0 = *reinterpret_cast<const float4*>(&As[kk][tm * 8]);
            const float4 xa1 = *reinterpret_cast<const float4*>(&As[kk][tm * 8 + 4]);
            const float4 xb0 = *reinterpret_cast<const float4*>(&Bs[kk][tn * 8]);
            const float4 xb1 = *reinterpret_cast<const float4*>(&Bs[kk][tn * 8 + 4]);
            const float av[8] = {xa0.x, xa0.y, xa0.z, xa0.w, xa1.x, xa1.y, xa1.z, xa1.w};
            const float bv[8] = {xb0.x, xb0.y, xb0.z, xb0.w, xb1.x, xb1.y, xb1.z, xb1.w};
#pragma unroll
            for (int i = 0; i < 8; ++i)
#pragma unroll
                for (int j = 0; j < 8; ++j) acc[i][j] = fmaf(av[i], bv[j], acc[i][j]);
        }
    }
    const int nb = n0 + tn * 8;
    float bias[8];
#pragma unroll
    for (int j = 0; j < 8; ++j) {
        float bbv = 0.0f;
        if (bias1) bbv += bias1[nb + j];
        if (bias2) bbv += bias2[nb + j];
        bias[j] = bbv;
    }
#pragma unroll
    for (int i = 0; i < 8; ++i) {
        const size_t m = (size_t)(m0 + tm * 8 + i);
        float o[8];
#pragma unroll
        for (int j = 0; j < 8; ++j) {
            float vv = acc[i][j] + bias[j];
            if (flags & 1) vv = tanh_precise(vv);
            o[j] = vv;
        }
        float4* pc = reinterpret_cast<float4*>(&C[m * N + nb]);
        pc[0] = make_float4(o[0], o[1], o[2], o[3]);
        pc[1] = make_float4(o[4], o[5], o[6], o[7]);
    }
}

// =====================================================================
// K3: bidirectional LSTM; grid 128 = 2 dirs * 64 groups; 512 threads;
// 2 batches/WG. W-pass compacted: runtime q-loop (unroll-2 lambda,
// double-buffered) to keep the step-loop body inside the I-cache.
// =====================================================================
__global__ __launch_bounds__(512, 2) void k_lstm(
    const float* __restrict__ Whh_f, const float* __restrict__ Whh_b,
    const float* __restrict__ xf, const float* __restrict__ xb,
    float* __restrict__ enc, float* __restrict__ hT, float* __restrict__ cT)
{
    const int wg = blockIdx.x;       // 0..127
    const int dir = wg >> 6;
    const int grp = wg & 63;
    const int bb0 = grp * 2;
    const float* W = dir ? Whh_b : Whh_f;
    const float* xin = dir ? xb : xf;
    const int tid = threadIdx.x;
    const int oct = tid & 7, jg = tid >> 3;   // jg 0..63
    const int gc = tid & 255, gb = tid >> 8;

    __shared__ __align__(16) float h_lds[2][256];
    __shared__ float pre_lds[2][1024];

    for (int i = tid; i < 2 * 256; i += 512) (&h_lds[0][0])[i] = 0.0f;
    float c_reg = 0.0f;
    __syncthreads();

    for (int t = 0; t < SS; ++t) {
        const int st = dir ? (SS - 1 - t) : t;
        float hreg[2][32];
#pragma unroll
        for (int bsel = 0; bsel < 2; ++bsel) {
#pragma unroll
            for (int i = 0; i < 8; ++i) {
                f32x4 v = ld4(&h_lds[bsel][i * 32 + oct * 4]);
                hreg[bsel][i * 4 + 0] = v.x; hreg[bsel][i * 4 + 1] = v.y;
                hreg[bsel][i * 4 + 2] = v.z; hreg[bsel][i * 4 + 3] = v.w;
            }
        }
        // W pass: 16 q-rounds of 64 rows, 1-ahead dbuf, compact loop
        {
            f32x4 wA[8], wB[8];
            {
                const float* bp = &W[(size_t)jg * 256 + oct * 4];
#pragma unroll
                for (int i = 0; i < 8; ++i) wA[i] = ld4(bp + i * 32);
            }
            auto wstep = [&](f32x4 (&cur)[8], f32x4 (&nxt)[8], int q) {
                if (q < 15) {
                    const float* bp = &W[(size_t)((q + 1) * 64 + jg) * 256 + oct * 4];
#pragma unroll
                    for (int i = 0; i < 8; ++i) nxt[i] = ld4(bp + i * 32);
                }
                float a0 = 0.0f, a1 = 0.0f;
#pragma unroll
                for (int i = 0; i < 8; ++i) {
                    a0 = fmaf(cur[i].x, hreg[0][i * 4 + 0], a0);
                    a0 = fmaf(cur[i].y, hreg[0][i * 4 + 1], a0);
                    a0 = fmaf(cur[i].z, hreg[0][i * 4 + 2], a0);
                    a0 = fmaf(cur[i].w, hreg[0][i * 4 + 3], a0);
                    a1 = fmaf(cur[i].x, hreg[1][i * 4 + 0], a1);
                    a1 = fmaf(cur[i].y, hreg[1][i * 4 + 1], a1);
                    a1 = fmaf(cur[i].z, hreg[1][i * 4 + 2], a1);
                    a1 = fmaf(cur[i].w, hreg[1][i * 4 + 3], a1);
                }
                a0 += __shfl_xor(a0, 1); a0 += __shfl_xor(a0, 2); a0 += __shfl_xor(a0, 4);
                a1 += __shfl_xor(a1, 1); a1 += __shfl_xor(a1, 2); a1 += __shfl_xor(a1, 4);
                if (oct == 0) {
                    const int row = q * 64 + jg;
                    pre_lds[0][row] = a0; pre_lds[1][row] = a1;
                }
            };
#pragma unroll 1
            for (int q = 0; q < 16; q += 2) { wstep(wA, wB, q); wstep(wB, wA, q + 1); }
        }
        __syncthreads();
        {
            const float* xrow = &xin[((size_t)(bb0 + gb) * SS + st) * 1024];
            float pi = pre_lds[gb][gc]       + ntload1(&xrow[gc]);
            float pf = pre_lds[gb][256 + gc] + ntload1(&xrow[256 + gc]);
            float pg = pre_lds[gb][512 + gc] + ntload1(&xrow[512 + gc]);
            float po = pre_lds[gb][768 + gc] + ntload1(&xrow[768 + gc]);
            float ig = sig_precise(pi), fg = sig_precise(pf);
            float gg = tanh_precise(pg), og = sig_precise(po);
            float cn = fmaf(fg, c_reg, ig * gg);
            float hn = og * tanh_precise(cn);
            c_reg = cn;
            h_lds[gb][gc] = hn;
            enc[((size_t)(bb0 + gb) * SS + st) * 512 + dir * 256 + gc] = hn;
            if (t == SS - 1) {
                hT[(size_t)(bb0 + gb) * 512 + dir * 256 + gc] = hn;
                cT[(size_t)(bb0 + gb) * 512 + dir * 256 + gc] = cn;
            }
        }
        __syncthreads();
    }
}

// =====================================================================
// K5: pre0[b][j] = mean_s encW[b][s][j]
// =====================================================================
__global__ __launch_bounds__(256) void k_meanw(const float* __restrict__ encW, float* __restrict__ pre0)
{
    const int b = blockIdx.x;
    const int tid = threadIdx.x;
    const float4* base = reinterpret_cast<const float4*>(&encW[(size_t)b * SS * 1024]);
    float sx = 0.0f, sy = 0.0f, sz = 0.0f, sw = 0.0f;
    for (int s = 0; s < SS; ++s) {
        float4 v = base[s * 256 + tid];
        sx += v.x; sy += v.y; sz += v.z; sw += v.w;
    }
    float4* out = reinterpret_cast<float4*>(&pre0[(size_t)b * 1024]);
    out[tid] = make_float4(sx * (1.0f / 128.0f), sy * (1.0f / 128.0f), sz * (1.0f / 128.0f), sw * (1.0f / 128.0f));
}

// =====================================================================
// K6: pointer decoder, 64 WGs x 2 batches, 512 threads, 128 steps.
// R8 semantics EXACTLY; code-size compaction only: all phase loops are
// runtime loops (#pragma unroll 1) with unroll-2 double-buffer lambdas,
// so the 128-iteration step body fits the 32 KB I-cache instead of
// re-streaming ~50 KB of instructions from L2 every step.
// =====================================================================
__global__ __launch_bounds__(512, 2) void k_decoder(
    const float* __restrict__ Whh_d,
    const float* __restrict__ gW2, const float* __restrict__ pW2,
    const float* __restrict__ gv, const float* __restrict__ pv,
    const float* __restrict__ g_ref, const float* __restrict__ p_ref,
    const float* __restrict__ encP, const float* __restrict__ encW,
    const float* __restrict__ pre0, const float* __restrict__ h0,
    const float* __restrict__ c0,
    float* __restrict__ out_logits, float* __restrict__ out_ptrs)
{
    const int b0 = blockIdx.x * 2;
    const int tid = threadIdx.x;
    const int oct = tid & 7, jg = tid >> 3;   // jg 0..63
    const int wid = tid >> 6, lane = tid & 63;

    __shared__ __align__(16) float h_lds[2][256];
    __shared__ float c_lds[2][256];
    __shared__ float pre_lds[2][1024];
    __shared__ float row_lds[2][1024];
    __shared__ __align__(16) float hgp[2][512];   // [.,0..255]=hg, [.,256..511]=hp1
    __shared__ __align__(16) float hp_lds[2][256];
    __shared__ __align__(16) float gv_lds[256];
    __shared__ __align__(16) float pv_lds[256];
    __shared__ float sc_arr[2][128];
    __shared__ float e_arr[2][128];
    __shared__ __align__(16) float hp_half[4][2][256];
    __shared__ int mask_lds[2][128];
    __shared__ float Z_arr[2];
    __shared__ int sel_arr[2];

    if (tid < 256) {
        gv_lds[tid] = gv[tid];
        pv_lds[tid] = pv[tid];
#pragma unroll
        for (int bt = 0; bt < 2; ++bt) {
            h_lds[bt][tid] = h0[(size_t)(b0 + bt) * 256 + tid];
            c_lds[bt][tid] = c0[(size_t)(b0 + bt) * 256 + tid];
        }
    }
    if (tid < 128) { mask_lds[0][tid] = 0; mask_lds[1][tid] = 0; }
    if (tid < 2) sel_arr[tid] = -1;
    __syncthreads();

    for (int t = 0; t < SS; ++t) {
        // ---- stage xt rows (encW[sel] or pre0); h_{t-1} -> regs ----
#pragma unroll 1
        for (int rep = 0; rep < 4; ++rep) {
            const int idx = tid + rep * 512;
            const int bt = idx >> 10, j = idx & 1023;
            const int sel = sel_arr[bt];
            const float* src = (sel < 0) ? &pre0[(size_t)(b0 + bt) * 1024]
                                         : &encW[((size_t)((b0 + bt) * SS + sel)) * 1024];
            row_lds[bt][j] = src[j];
        }
        float hreg[2][32];
#pragma unroll
        for (int bt = 0; bt < 2; ++bt) {
#pragma unroll
            for (int i = 0; i < 8; ++i) {
                f32x4 v = ld4(&h_lds[bt][i * 32 + oct * 4]);
                hreg[bt][i * 4 + 0] = v.x; hreg[bt][i * 4 + 1] = v.y;
                hreg[bt][i * 4 + 2] = v.z; hreg[bt][i * 4 + 3] = v.w;
            }
        }
        __syncthreads();
        // ---- phase 1: pre = row + Whh_d @ h (16 rounds, compact dbuf) ----
        {
            f32x4 wA[8], wB[8];
            {
                const float* bp = &Whh_d[(size_t)jg * 256 + oct * 4];
#pragma unroll
                for (int i = 0; i < 8; ++i) wA[i] = ld4(bp + i * 32);
            }
            auto p1 = [&](f32x4 (&cur)[8], f32x4 (&nxt)[8], int q) {
                if (q < 15) {
                    const float* bp = &Whh_d[(size_t)((q + 1) * 64 + jg) * 256 + oct * 4];
#pragma unroll
                    for (int i = 0; i < 8; ++i) nxt[i] = ld4(bp + i * 32);
                }
                float a0 = 0.0f, a1 = 0.0f;
#pragma unroll
                for (int i = 0; i < 8; ++i) {
                    a0 = fmaf(cur[i].x, hreg[0][i * 4 + 0], a0);
                    a0 = fmaf(cur[i].y, hreg[0][i * 4 + 1], a0);
                    a0 = fmaf(cur[i].z, hreg[0][i * 4 + 2], a0);
                    a0 = fmaf(cur[i].w, hreg[0][i * 4 + 3], a0);
                    a1 = fmaf(cur[i].x, hreg[1][i * 4 + 0], a1);
                    a1 = fmaf(cur[i].y, hreg[1][i * 4 + 1], a1);
                    a1 = fmaf(cur[i].z, hreg[1][i * 4 + 2], a1);
                    a1 = fmaf(cur[i].w, hreg[1][i * 4 + 3], a1);
                }
                a0 += __shfl_xor(a0, 1); a0 += __shfl_xor(a0, 2); a0 += __shfl_xor(a0, 4);
                a1 += __shfl_xor(a1, 1); a1 += __shfl_xor(a1, 2); a1 += __shfl_xor(a1, 4);
                if (oct == 0) {
                    const int row = q * 64 + jg;
                    pre_lds[0][row] = a0 + row_lds[0][row];
                    pre_lds[1][row] = a1 + row_lds[1][row];
                }
            };
#pragma unroll 1
            for (int q = 0; q < 16; q += 2) { p1(wA, wB, q); p1(wB, wA, q + 1); }
        }
        __syncthreads();
        // ---- phase 2: gates ----
        {
            const int bt = tid >> 8, ch = tid & 255;
            float pi = pre_lds[bt][ch],        pf = pre_lds[bt][256 + ch];
            float pg = pre_lds[bt][512 + ch],  po = pre_lds[bt][768 + ch];
            float ig = sig_precise(pi), fg = sig_precise(pf);
            float gg = tanh_precise(pg), og = sig_precise(po);
            float cn = fmaf(fg, c_lds[bt][ch], ig * gg);
            float hn = og * tanh_precise(cn);
            c_lds[bt][ch] = cn;
            h_lds[bt][ch] = hn;
        }
        __syncthreads();
        // reload new h slices
        float hreg2[2][32];
#pragma unroll
        for (int bt = 0; bt < 2; ++bt) {
#pragma unroll
            for (int i = 0; i < 8; ++i) {
                f32x4 v = ld4(&h_lds[bt][i * 32 + oct * 4]);
                hreg2[bt][i * 4 + 0] = v.x; hreg2[bt][i * 4 + 1] = v.y;
                hreg2[bt][i * 4 + 2] = v.z; hreg2[bt][i * 4 + 3] = v.w;
            }
        }
        // ---- phase 3: hg = h@gW2.T (rows 0..255), hp1 = h@pW2.T (256..511) ----
        {
            f32x4 wA[8], wB[8];
            {
                const float* bp = &gW2[(size_t)jg * 256 + oct * 4];
#pragma unroll
                for (int i = 0; i < 8; ++i) wA[i] = ld4(bp + i * 32);
            }
            auto p3 = [&](f32x4 (&cur)[8], f32x4 (&nxt)[8], int q) {
                if (q < 7) {
                    const int r2 = (q + 1) * 64 + jg;
                    const float* src = (r2 < 256) ? &gW2[(size_t)r2 * 256] : &pW2[(size_t)(r2 - 256) * 256];
#pragma unroll
                    for (int i = 0; i < 8; ++i) nxt[i] = ld4(src + oct * 4 + i * 32);
                }
                float a0 = 0.0f, a1 = 0.0f;
#pragma unroll
                for (int i = 0; i < 8; ++i) {
                    a0 = fmaf(cur[i].x, hreg2[0][i * 4 + 0], a0);
                    a0 = fmaf(cur[i].y, hreg2[0][i * 4 + 1], a0);
                    a0 = fmaf(cur[i].z, hreg2[0][i * 4 + 2], a0);
                    a0 = fmaf(cur[i].w, hreg2[0][i * 4 + 3], a0);
                    a1 = fmaf(cur[i].x, hreg2[1][i * 4 + 0], a1);
                    a1 = fmaf(cur[i].y, hreg2[1][i * 4 + 1], a1);
                    a1 = fmaf(cur[i].z, hreg2[1][i * 4 + 2], a1);
                    a1 = fmaf(cur[i].w, hreg2[1][i * 4 + 3], a1);
                }
                a0 += __shfl_xor(a0, 1); a0 += __shfl_xor(a0, 2); a0 += __shfl_xor(a0, 4);
                a1 += __shfl_xor(a1, 1); a1 += __shfl_xor(a1, 2); a1 += __shfl_xor(a1, 4);
                if (oct == 0) {
                    const int row = q * 64 + jg;
                    hgp[0][row] = a0; hgp[1][row] = a1;
                }
            };
#pragma unroll 1
            for (int q = 0; q < 8; q += 2) { p3(wA, wB, q); p3(wB, wA, q + 1); }
        }
        __syncthreads();
        // ---- phase 4: gs scores (compact dbuf over 4 reps) ----
        {
            f32x4 gA[8], gB[8];
            {
                const float* gr = &g_ref[((size_t)(b0 * SS + jg)) * 256 + oct * 4];
#pragma unroll
                for (int i = 0; i < 8; ++i) gA[i] = ld4(gr + i * 32);
            }
            auto p4 = [&](f32x4 (&cur)[8], f32x4 (&nxt)[8], int rep) {
                const int bt = rep & 1;
                const int r = jg + ((rep >> 1) << 6);
                if (rep < 3) {
                    const int btn = (rep + 1) & 1, rn = jg + (((rep + 1) >> 1) << 6);
                    const float* gr = &g_ref[((size_t)((b0 + btn) * SS + rn)) * 256 + oct * 4];
#pragma unroll
                    for (int i = 0; i < 8; ++i) nxt[i] = ld4(gr + i * 32);
                }
                float part = 0.0f;
#pragma unroll
                for (int i = 0; i < 8; ++i) {
                    const int d = i * 32 + oct * 4;
                    const f32x4 hh = ld4(&hgp[bt][d]);
                    const f32x4 vv = ld4(&gv_lds[d]);
                    part = fmaf(ftanh_fast(cur[i].x + hh.x), vv.x, part);
                    part = fmaf(ftanh_fast(cur[i].y + hh.y), vv.y, part);
                    part = fmaf(ftanh_fast(cur[i].z + hh.z), vv.z, part);
                    part = fmaf(ftanh_fast(cur[i].w + hh.w), vv.w, part);
                }
                part += __shfl_xor(part, 1); part += __shfl_xor(part, 2); part += __shfl_xor(part, 4);
                if (oct == 0) sc_arr[bt][r] = mask_lds[bt][r] ? -1e9f : part * 0.0625f;
            };
#pragma unroll 1
            for (int rep = 0; rep < 4; rep += 2) { p4(gA, gB, rep); p4(gB, gA, rep + 1); }
        }
        __syncthreads();
        // ---- phase 5: softmax (2 waves) ----
        if (wid < 2) {
            const int bt = wid;
            float s0 = sc_arr[bt][lane], s1 = sc_arr[bt][lane + 64];
            float m = fmaxf(s0, s1);
#pragma unroll
            for (int mk = 1; mk < 64; mk <<= 1) m = fmaxf(m, __shfl_xor(m, mk));
            float e0 = expf(s0 - m), e1 = expf(s1 - m);
            e_arr[bt][lane] = e0; e_arr[bt][lane + 64] = e1;
            float z = e0 + e1;
#pragma unroll
            for (int mk = 1; mk < 64; mk <<= 1) z += __shfl_xor(z, mk);
            if (lane == 0) Z_arr[bt] = z;
        }
        __syncthreads();
        // ---- phase 6: ctx partials (compact dbuf over 4 groups) ----
        {
            const int bt6 = wid & 1, sq = wid >> 1;   // sq 0..3, 32 s each
            const int d4 = lane * 4;
            const float* base6 = &encP[((size_t)((b0 + bt6) * SS + sq * 32)) * 256 + d4];
            float ax = 0.0f, ay = 0.0f, az = 0.0f, aw = 0.0f;
            f32x4 pA[8], pB[8];
#pragma unroll
            for (int i = 0; i < 8; ++i) pA[i] = ld4(base6 + i * 256);
            auto p6 = [&](f32x4 (&cur)[8], f32x4 (&nxt)[8], int g) {
                if (g < 3) {
#pragma unroll
                    for (int i = 0; i < 8; ++i) nxt[i] = ld4(base6 + (g + 1) * 8 * 256 + i * 256);
                }
#pragma unroll
                for (int i = 0; i < 8; ++i) {
                    const float e = e_arr[bt6][sq * 32 + g * 8 + i];
                    ax = fmaf(cur[i].x, e, ax); ay = fmaf(cur[i].y, e, ay);
                    az = fmaf(cur[i].z, e, az); aw = fmaf(cur[i].w, e, aw);
                }
            };
#pragma unroll 1
            for (int g = 0; g < 4; g += 2) { p6(pA, pB, g); p6(pB, pA, g + 1); }
            *reinterpret_cast<float4*>(&hp_half[sq][bt6][d4]) = make_float4(ax, ay, az, aw);
        }
        __syncthreads();
        {
            const int bt = tid >> 8, d = tid & 255;
            hp_lds[bt][d] = hgp[bt][256 + d] +
                            (hp_half[0][bt][d] + hp_half[1][bt][d] +
                             hp_half[2][bt][d] + hp_half[3][bt][d]) * frcp(Z_arr[bt]);
        }
        __syncthreads();
        // ---- phase 7: ps scores (compact dbuf over 4 reps) ----
        {
            f32x4 gA[8], gB[8];
            {
                const float* pr = &p_ref[((size_t)(b0 * SS + jg)) * 256 + oct * 4];
#pragma unroll
                for (int i = 0; i < 8; ++i) gA[i] = ld4(pr + i * 32);
            }
            auto p7 = [&](f32x4 (&cur)[8], f32x4 (&nxt)[8], int rep) {
                const int bt = rep & 1;
                const int r = jg + ((rep >> 1) << 6);
                if (rep < 3) {
                    const int btn = (rep + 1) & 1, rn = jg + (((rep + 1) >> 1) << 6);
                    const float* pr = &p_ref[((size_t)((b0 + btn) * SS + rn)) * 256 + oct * 4];
#pragma unroll
                    for (int i = 0; i < 8; ++i) nxt[i] = ld4(pr + i * 32);
                }
                float part = 0.0f;
#pragma unroll
                for (int i = 0; i < 8; ++i) {
                    const int d = i * 32 + oct * 4;
                    const f32x4 hh = ld4(&hp_lds[bt][d]);
                    const f32x4 vv = ld4(&pv_lds[d]);
                    part = fmaf(ftanh_fast(cur[i].x + hh.x), vv.x, part);
                    part = fmaf(ftanh_fast(cur[i].y + hh.y), vv.y, part);
                    part = fmaf(ftanh_fast(cur[i].z + hh.z), vv.z, part);
                    part = fmaf(ftanh_fast(cur[i].w + hh.w), vv.w, part);
                }
                part += __shfl_xor(part, 1); part += __shfl_xor(part, 2); part += __shfl_xor(part, 4);
                if (oct == 0) sc_arr[bt][r] = mask_lds[bt][r] ? -1e9f : part * 0.0625f;
            };
#pragma unroll 1
            for (int rep = 0; rep < 4; rep += 2) { p7(gA, gB, rep); p7(gB, gA, rep + 1); }
        }
        __syncthreads();
        // ---- phase 8: logits write + argmax (first-max semantics) ----
        if (tid < 256) {
            const int bt = tid >> 7, s = tid & 127;
            out_logits[((size_t)((b0 + bt) * SS + t)) * SS + s] = sc_arr[bt][s];
        }
        if (wid < 2) {
            const int bt = wid;
            float v = sc_arr[bt][lane];
            int idx = lane;
            float v2 = sc_arr[bt][lane + 64];
            if (v2 > v) { v = v2; idx = lane + 64; }
#pragma unroll
            for (int mk = 1; mk < 64; mk <<= 1) {
                float ov = __shfl_xor(v, mk);
                int oi = __shfl_xor(idx, mk);
                if (ov > v || (ov == v && oi < idx)) { v = ov; idx = oi; }
            }
            if (lane == 0) {
                sel_arr[bt] = idx;
                mask_lds[bt][idx] = 1;
                out_ptrs[(size_t)(b0 + bt) * SS + t] = (float)idx;
            }
        }
        __syncthreads();
    }
}

// =====================================================================
// host launcher
// =====================================================================
extern "C" void kernel_launch(void* const* d_in, const int* in_sizes, int n_in,
                              void* d_out, int out_size, void* d_ws, size_t ws_size,
                              hipStream_t stream)
{
    (void)in_sizes; (void)n_in; (void)out_size; (void)ws_size;
    const float* x      = (const float*)d_in[0];
    const float* proj_W = (const float*)d_in[1];
    const float* proj_b = (const float*)d_in[2];
    const float* ln_g   = (const float*)d_in[3];
    const float* ln_b   = (const float*)d_in[4];
    const float* Wih_f  = (const float*)d_in[5];
    const float* Whh_f  = (const float*)d_in[6];
    const float* bih_f  = (const float*)d_in[7];
    const float* bhh_f  = (const float*)d_in[8];
    const float* Wih_b  = (const float*)d_in[9];
    const float* Whh_b  = (const float*)d_in[10];
    const float* bih_b  = (const float*)d_in[11];
    const float* bhh_b  = (const float*)d_in[12];
    const float* Wih_d  = (const float*)d_in[13];
    const float* Whh_d  = (const float*)d_in[14];
    const float* bih_d  = (const float*)d_in[15];
    const float* bhh_d  = (const float*)d_in[16];
    const float* hb_W   = (const float*)d_in[17];
    const float* hb_b   = (const float*)d_in[18];
    const float* cb_W   = (const float*)d_in[19];
    const float* cb_b   = (const float*)d_in[20];
    const float* gW1    = (const float*)d_in[21];
    const float* gW2    = (const float*)d_in[22];
    const float* gv     = (const float*)d_in[23];
    const float* pW1    = (const float*)d_in[24];
    const float* pW2    = (const float*)d_in[25];
    const float* pv     = (const float*)d_in[26];

    float* ws = (float*)d_ws;
    const size_t o_hT    = 0;
    const size_t o_cT    = 65536;
    const size_t o_h0    = 131072;
    const size_t o_c0    = 163840;
    const size_t o_pre0  = 196608;
    const size_t o_emb   = 0;
    const size_t o_xf    = 4194304;
    const size_t o_xb    = o_xf + 16777216;
    const size_t o_enc   = o_xb + 16777216;
    const size_t o_encW  = o_xf;
    const size_t o_gref  = o_xb;
    const size_t o_pref  = o_xb + 4194304;
    const size_t o_encP  = o_xb + 8388608;

    float* emb  = ws + o_emb;
    float* xf   = ws + o_xf;
    float* xb   = ws + o_xb;
    float* enc  = ws + o_enc;
    float* hT   = ws + o_hT;
    float* cT   = ws + o_cT;
    float* h0b  = ws + o_h0;
    float* c0b  = ws + o_c0;
    float* pre0 = ws + o_pre0;
    float* encW = ws + o_encW;
    float* gref = ws + o_gref;
    float* pref = ws + o_pref;
    float* encP = ws + o_encP;

    float* out_logits = (float*)d_out;
    float* out_ptrs   = out_logits + (size_t)BB * SS * SS;

    // 1. emb
    k_proj_ln<<<BB * SS, 256, 0, stream>>>(x, proj_W, proj_b, ln_g, ln_b, emb);
    // 2-3. xf / xb  (bias = bih + bhh)
    {
        dim3 g(128, 8);
        k_gemm_nt<<<g, 256, 0, stream>>>(emb, 256, Wih_f, xf, 16384, 1024, 256, bih_f, bhh_f, 0);
        k_gemm_nt<<<g, 256, 0, stream>>>(emb, 256, Wih_b, xb, 16384, 1024, 256, bih_b, bhh_b, 0);
    }
    // 4. LSTM both directions
    k_lstm<<<128, 512, 0, stream>>>(Whh_f, Whh_b, xf, xb, enc, hT, cT);
    // 5-6. h0 / c0
    {
        dim3 g(1, 2);
        k_gemm_nt<<<g, 256, 0, stream>>>(hT, 512, hb_W, h0b, 128, 256, 512, hb_b, nullptr, 1);
        k_gemm_nt<<<g, 256, 0, stream>>>(cT, 512, cb_W, c0b, 128, 256, 512, cb_b, nullptr, 1);
    }
    // 7-10. attention precomputes
    {
        dim3 g2(128, 2);
        k_gemm_nt<<<g2, 256, 0, stream>>>(enc, 512, gW1, gref, 16384, 256, 512, nullptr, nullptr, 0);
        k_gemm_nt<<<g2, 256, 0, stream>>>(enc, 512, pW1, pref, 16384, 256, 512, nullptr, nullptr, 0);
        dim3 g1(128, 8);
        k_gemm_nt<<<g1, 256, 0, stream>>>(enc, 512, Wih_d, encW, 16384, 1024, 512, bih_d, bhh_d, 0);
        k_gemm_nt<<<g2, 256, 0, stream>>>(enc, 512, pW2, encP, 16384, 256, 256, nullptr, nullptr, 0);
    }
    // 11. pre0 = mean_s encW
    k_meanw<<<BB, 256, 0, stream>>>(encW, pre0);
    // 12. decoder: 64 WGs x 2 batches, compact step-loop body (I$-resident)
    k_decoder<<<64, 512, 0, stream>>>(Whh_d, gW2, pW2, gv, pv, gref, pref, encP, encW,
                                      pre0, h0b, c0b, out_logits, out_ptrs);
}